// Round 1
// baseline (1165.423 us; speedup 1.0000x reference)
//
#include <hip/hip_runtime.h>
#include <hip/hip_bf16.h>

// EncoderLayer: B=4,S=2048,D=1024,H=16,DH=64,DFF=4096
// Pipeline (all bf16 MFMA, fp32 accum):
//   prep(convert/transpose) -> GEMM0 qkv -> flash-attn -> GEMM1 Wo -> GEMM2 W1+relu -> GEMM3 W2 -> d_out(fp32)

#define SDIM 2048
#define DDIM 1024

using floatx4 = __attribute__((ext_vector_type(4))) float;
using bf16x8  = __attribute__((ext_vector_type(8))) __bf16;
using bf16x4  = __attribute__((ext_vector_type(4))) __bf16;

// ---------------- prep kernels ----------------

__global__ void k_f2b(const float* __restrict__ in, __bf16* __restrict__ out) {
    long i = ((long)blockIdx.x * 256 + threadIdx.x) * 4;
    float4 f = *(const float4*)(in + i);
    bf16x4 v;
    v[0] = (__bf16)f.x; v[1] = (__bf16)f.y; v[2] = (__bf16)f.z; v[3] = (__bf16)f.w;
    *(bf16x4*)(out + i) = v;
}

// transpose-convert: out[c][r] = (bf16) in[r][c], R,C multiples of 32, grid=(R/32)*(C/32)
__global__ void k_tr(const float* __restrict__ in, __bf16* __restrict__ out, int R, int C) {
    __shared__ float t[32][33];
    int nrt = R >> 5;
    int tr = blockIdx.x % nrt, tc = blockIdx.x / nrt;
    int r0 = tr * 32, c0 = tc * 32;
    int lx = threadIdx.x & 31, ly = threadIdx.x >> 5; // 32x8
    #pragma unroll
    for (int i = 0; i < 32; i += 8) t[ly + i][lx] = in[(long)(r0 + ly + i) * C + c0 + lx];
    __syncthreads();
    #pragma unroll
    for (int i = 0; i < 32; i += 8) out[(long)(c0 + ly + i) * R + r0 + lx] = (__bf16)t[lx][ly + i];
}

// pack Wq/Wk/Wv [16][1024][64] -> Wqkvt[n=(which*1024+h*64+dh)][d=1024] bf16
// grid = 3*16*32*2 = 3072 blocks of 256
__global__ void k_pack_qkvw(const float* __restrict__ Wq, const float* __restrict__ Wk,
                            const float* __restrict__ Wv, __bf16* __restrict__ out) {
    int bid = blockIdx.x;
    int dht = bid & 1;
    int dt = (bid >> 1) & 31;
    int h = (bid >> 6) & 15;
    int which = bid >> 10;
    const float* W = (which == 0) ? Wq : (which == 1) ? Wk : Wv;
    __shared__ float t[32][33];
    int lx = threadIdx.x & 31, ly = threadIdx.x >> 5;
    const float* src = W + ((long)h * 1024 + dt * 32) * 64 + dht * 32;
    #pragma unroll
    for (int i = 0; i < 32; i += 8) t[ly + i][lx] = src[(ly + i) * 64 + lx];
    __syncthreads();
    __bf16* dst = out + ((long)(which * 1024 + h * 64 + dht * 32)) * 1024 + dt * 32;
    #pragma unroll
    for (int i = 0; i < 32; i += 8) dst[(long)(ly + i) * 1024 + lx] = (__bf16)t[lx][ly + i];
}

__global__ void k_pack_qkvb(const float* bq, const float* bk, const float* bv, float* out) {
    int i = blockIdx.x * 256 + threadIdx.x;
    if (i < 3072) {
        int which = i >> 10, r = i & 1023;
        const float* s = (which == 0) ? bq : (which == 1) ? bk : bv;
        out[i] = s[r];
    }
}

// mask storage probe: flag=1 -> 4-byte records (int32/float), flag=0 -> 1-byte records
__global__ void k_probe(const unsigned* __restrict__ m, int* flag) {
    __shared__ int bad;
    if (threadIdx.x == 0) bad = 0;
    __syncthreads();
    int local = 0;
    for (int i = 0; i < 64; i++) {
        unsigned w = m[threadIdx.x + 256 * i];
        if (w != 0u && w != 1u && w != 0x3f800000u) local = 1;
    }
    if (local) atomicOr(&bad, 1);
    __syncthreads();
    if (threadIdx.x == 0) *flag = bad ? 0 : 1;
}

// ---------------- GEMM: C[M,N] = A[M,K] @ Bt[N,K]^T + bias, epilogue by MODE ----------------
// MODE 0: scatter to Q/K/Vt (N=3072), Cout = Q base; Q[pair][s][dh], K same (+QSZ), Vt[pair][dh][s] (+2*QSZ)
// MODE 1: bf16 row-major [M][N]
// MODE 2: relu + bf16 row-major
// MODE 3: fp32 row-major (final output)
#define QSZ 8388608L

template <int MODE>
__global__ __launch_bounds__(256, 2) void k_gemm(const __bf16* __restrict__ A,
                                                 const __bf16* __restrict__ Bt,
                                                 const float* __restrict__ bias,
                                                 void* __restrict__ Cout, int Ndim, int K) {
    __shared__ __align__(16) __bf16 As[128][40];
    __shared__ __align__(16) __bf16 Bs[128][40];
    const int tid = threadIdx.x;
    const int wave = tid >> 6, lane = tid & 63;
    const int q = lane >> 4, l16 = lane & 15;
    const int wr = wave >> 1, wc = wave & 1;
    const long bm = (long)blockIdx.x * 128;
    const long bn = (long)blockIdx.y * 128;
    floatx4 acc[4][4] = {};

    const int srow0 = tid >> 2;
    const int sc8 = (tid & 3) * 8;

    for (int k0 = 0; k0 < K; k0 += 32) {
        __syncthreads();
        #pragma unroll
        for (int i = 0; i < 2; i++) {
            int row = srow0 + i * 64;
            *(bf16x8*)&As[row][sc8] = *(const bf16x8*)&A[(bm + row) * K + k0 + sc8];
            *(bf16x8*)&Bs[row][sc8] = *(const bf16x8*)&Bt[(bn + row) * K + k0 + sc8];
        }
        __syncthreads();
        bf16x8 af[4], bfr[4];
        #pragma unroll
        for (int i = 0; i < 4; i++) af[i] = *(const bf16x8*)&As[wr * 64 + i * 16 + l16][q * 8];
        #pragma unroll
        for (int j = 0; j < 4; j++) bfr[j] = *(const bf16x8*)&Bs[wc * 64 + j * 16 + l16][q * 8];
        #pragma unroll
        for (int i = 0; i < 4; i++)
            #pragma unroll
            for (int j = 0; j < 4; j++)
                acc[i][j] = __builtin_amdgcn_mfma_f32_16x16x32_bf16(af[i], bfr[j], acc[i][j], 0, 0, 0);
    }

    const int mrow0 = (int)bm + wr * 64 + q * 4;
    const int ncol0 = (int)bn + wc * 64;
    #pragma unroll
    for (int j = 0; j < 4; j++) {
        int nbase = ncol0 + j * 16 + l16;
        float bv = bias[nbase];
        #pragma unroll
        for (int i = 0; i < 4; i++) {
            #pragma unroll
            for (int r = 0; r < 4; r++) {
                int mm = mrow0 + i * 16 + r;
                float v = acc[i][j][r] + bv;
                if (MODE == 2) v = fmaxf(v, 0.f);
                if (MODE == 3) {
                    ((float*)Cout)[(long)mm * Ndim + nbase] = v;
                } else if (MODE == 0) {
                    int which = nbase >> 10, rem = nbase & 1023;
                    int hh = rem >> 6, dh = rem & 63;
                    int bb = mm >> 11, ss = mm & 2047;
                    long pr = (long)(bb * 16 + hh);
                    __bf16* o = (__bf16*)Cout;
                    if (which == 0) o[(pr * 2048 + ss) * 64 + dh] = (__bf16)v;
                    else if (which == 1) o[QSZ + (pr * 2048 + ss) * 64 + dh] = (__bf16)v;
                    else o[2 * QSZ + (pr * 64 + dh) * 2048 + ss] = (__bf16)v;
                } else {
                    ((__bf16*)Cout)[(long)mm * Ndim + nbase] = (__bf16)v;
                }
            }
        }
    }
}

// ---------------- flash attention ----------------
// grid = 64 pairs * 32 q-tiles = 2048 blocks, 256 threads (4 waves, 16 q-rows each)
__global__ __launch_bounds__(256, 2) void k_attn(const __bf16* __restrict__ Q,
                                                 const __bf16* __restrict__ Kb,
                                                 const __bf16* __restrict__ Vt,
                                                 const unsigned char* __restrict__ mask_b,
                                                 const int* __restrict__ flag,
                                                 __bf16* __restrict__ ctx) {
    __shared__ __align__(16) __bf16 Qs[64][72];
    __shared__ __align__(16) __bf16 Ks[128][72];
    __shared__ __align__(16) __bf16 Vts[64][136];
    __shared__ __align__(16) __bf16 Ps[4][16][136];
    const int tid = threadIdx.x, wave = tid >> 6, lane = tid & 63;
    const int q = lane >> 4, l16 = lane & 15;
    const int pair = blockIdx.x >> 5, qt = blockIdx.x & 31;
    const int b = pair >> 4, h = pair & 15;
    const int mmode = *flag;

    const __bf16* Qp = Q + ((long)pair * SDIM + qt * 64) * 64;
    #pragma unroll
    for (int i = 0; i < 2; i++) {
        int v = tid + i * 256;
        int r = v >> 3, c = (v & 7) * 8;
        *(bf16x8*)&Qs[r][c] = *(const bf16x8*)&Qp[r * 64 + c];
    }

    float mrun[4], lrun[4];
    floatx4 o[4];
    #pragma unroll
    for (int r = 0; r < 4; r++) { mrun[r] = -INFINITY; lrun[r] = 0.f; }
    #pragma unroll
    for (int d = 0; d < 4; d++) o[d] = (floatx4){0.f, 0.f, 0.f, 0.f};

    const float scale = 0.02209708691207961f; // 1/sqrt(2048)
    const int qrow0 = qt * 64 + wave * 16 + q * 4;

    for (int kt = 0; kt < 16; kt++) {
        __syncthreads();
        const __bf16* Kp = Kb + ((long)pair * SDIM + kt * 128) * 64;
        #pragma unroll
        for (int i = 0; i < 4; i++) {
            int v = tid + i * 256;
            int r = v >> 3, c = (v & 7) * 8;
            *(bf16x8*)&Ks[r][c] = *(const bf16x8*)&Kp[r * 64 + c];
        }
        const __bf16* Vp = Vt + (long)pair * 64 * SDIM + kt * 128;
        #pragma unroll
        for (int i = 0; i < 4; i++) {
            int v = tid + i * 256;
            int r = v >> 4, c = (v & 15) * 8;
            *(bf16x8*)&Vts[r][c] = *(const bf16x8*)&Vp[(long)r * SDIM + c];
        }
        __syncthreads();

        // S = Q K^T
        bf16x8 a0 = *(const bf16x8*)&Qs[wave * 16 + l16][q * 8];
        bf16x8 a1 = *(const bf16x8*)&Qs[wave * 16 + l16][32 + q * 8];
        floatx4 s[8];
        #pragma unroll
        for (int ct = 0; ct < 8; ct++) {
            bf16x8 b0 = *(const bf16x8*)&Ks[ct * 16 + l16][q * 8];
            bf16x8 b1 = *(const bf16x8*)&Ks[ct * 16 + l16][32 + q * 8];
            floatx4 z = {};
            z = __builtin_amdgcn_mfma_f32_16x16x32_bf16(a0, b0, z, 0, 0, 0);
            z = __builtin_amdgcn_mfma_f32_16x16x32_bf16(a1, b1, z, 0, 0, 0);
            s[ct] = z;
        }
        // scale + mask
        #pragma unroll
        for (int ct = 0; ct < 8; ct++) {
            int col = kt * 128 + ct * 16 + l16;
            #pragma unroll
            for (int r = 0; r < 4; r++) {
                long midx = ((long)b * SDIM + (qrow0 + r)) * SDIM + col;
                bool msk = mmode ? (((const unsigned*)mask_b)[midx] != 0u) : (mask_b[midx] != 0);
                float v = s[ct][r] * scale;
                s[ct][r] = msk ? -1e9f : v;
            }
        }
        // row max (across 8 col-tiles then 16-lane group)
        float mnew[4], alpha[4];
        #pragma unroll
        for (int r = 0; r < 4; r++) {
            float v = s[0][r];
            #pragma unroll
            for (int ct = 1; ct < 8; ct++) v = fmaxf(v, s[ct][r]);
            #pragma unroll
            for (int off = 1; off < 16; off <<= 1) v = fmaxf(v, __shfl_xor(v, off));
            mnew[r] = fmaxf(mrun[r], v);
            alpha[r] = __expf(mrun[r] - mnew[r]);
            mrun[r] = mnew[r];
        }
        // p = exp(s - m), row sum
        float rs[4] = {0.f, 0.f, 0.f, 0.f};
        #pragma unroll
        for (int ct = 0; ct < 8; ct++)
            #pragma unroll
            for (int r = 0; r < 4; r++) {
                float p = __expf(s[ct][r] - mnew[r]);
                s[ct][r] = p;
                rs[r] += p;
            }
        #pragma unroll
        for (int r = 0; r < 4; r++) {
            float v = rs[r];
            #pragma unroll
            for (int off = 1; off < 16; off <<= 1) v += __shfl_xor(v, off);
            lrun[r] = lrun[r] * alpha[r] + v;
        }
        #pragma unroll
        for (int d = 0; d < 4; d++)
            #pragma unroll
            for (int r = 0; r < 4; r++) o[d][r] *= alpha[r];
        // P -> LDS (C-layout -> A-layout transform)
        #pragma unroll
        for (int ct = 0; ct < 8; ct++)
            #pragma unroll
            for (int r = 0; r < 4; r++)
                Ps[wave][q * 4 + r][ct * 16 + l16] = (__bf16)s[ct][r];
        __syncthreads();
        // O += P V
        #pragma unroll
        for (int kk = 0; kk < 4; kk++) {
            bf16x8 ap = *(const bf16x8*)&Ps[wave][l16][kk * 32 + q * 8];
            #pragma unroll
            for (int d = 0; d < 4; d++) {
                bf16x8 bv = *(const bf16x8*)&Vts[d * 16 + l16][kk * 32 + q * 8];
                o[d] = __builtin_amdgcn_mfma_f32_16x16x32_bf16(ap, bv, o[d], 0, 0, 0);
            }
        }
    }
    // epilogue: ctx[b][s][h*64+dh] = o / l
    #pragma unroll
    for (int r = 0; r < 4; r++) {
        float inv = 1.0f / lrun[r];
        int row = qrow0 + r;
        long base = ((long)b * SDIM + row) * DDIM + h * 64;
        #pragma unroll
        for (int d = 0; d < 4; d++) ctx[base + d * 16 + l16] = (__bf16)(o[d][r] * inv);
    }
}

// ---------------- launch ----------------

extern "C" void kernel_launch(void* const* d_in, const int* in_sizes, int n_in,
                              void* d_out, int out_size, void* d_ws, size_t ws_size,
                              hipStream_t stream) {
    const float* x = (const float*)d_in[0];
    const void* mask = d_in[1];
    const float* Wq = (const float*)d_in[2];
    const float* bq = (const float*)d_in[3];
    const float* Wk = (const float*)d_in[4];
    const float* bk = (const float*)d_in[5];
    const float* Wv = (const float*)d_in[6];
    const float* bv = (const float*)d_in[7];
    const float* Wo = (const float*)d_in[8];
    const float* bo = (const float*)d_in[9];
    const float* W1 = (const float*)d_in[10];
    const float* b1 = (const float*)d_in[11];
    const float* W2 = (const float*)d_in[12];
    const float* b2 = (const float*)d_in[13];

    char* ws = (char*)d_ws;
    // layout (bytes):
    __bf16* xb   = (__bf16*)(ws + 0);          // 16 MB; aliased as ctx after GEMM0
    __bf16* Qb   = (__bf16*)(ws + 16777216);   // 16 MB; aliased as attn_out after attention
    __bf16* Kb   = (__bf16*)(ws + 33554432);   // 16 MB
    __bf16* Vtb  = (__bf16*)(ws + 50331648);   // 16 MB
    __bf16* hbuf = (__bf16*)(ws + 33554432);   // 64 MB (aliases K,Vt after attention)
    __bf16* wqkvt = (__bf16*)(ws + 100663296); // 6 MB
    __bf16* wot  = (__bf16*)(ws + 106954752);  // 2 MB
    __bf16* w1t  = (__bf16*)(ws + 109051904);  // 8 MB
    __bf16* w2t  = (__bf16*)(ws + 117440512);  // 8 MB
    float* bqkv  = (float*)(ws + 125829120);   // 12 KB
    int* flag    = (int*)(ws + 125841408);     // 4 B
    __bf16* ctx = xb;
    __bf16* attn_out = Qb;

    // prep
    k_f2b<<<8192, 256, 0, stream>>>(x, xb);
    k_pack_qkvw<<<3072, 256, 0, stream>>>(Wq, Wk, Wv, wqkvt);
    k_pack_qkvb<<<12, 256, 0, stream>>>(bq, bk, bv, bqkv);
    k_tr<<<1024, 256, 0, stream>>>(Wo, wot, 1024, 1024);
    k_tr<<<4096, 256, 0, stream>>>(W1, w1t, 1024, 4096);
    k_tr<<<4096, 256, 0, stream>>>(W2, w2t, 4096, 1024);
    k_probe<<<1, 256, 0, stream>>>((const unsigned*)mask, flag);

    // QKV projection: [8192,1024] x [3072,1024]^T
    {
        dim3 g(64, 24);
        k_gemm<0><<<g, 256, 0, stream>>>(xb, wqkvt, bqkv, (void*)Qb, 3072, 1024);
    }
    // attention
    k_attn<<<2048, 256, 0, stream>>>(Qb, Kb, Vtb, (const unsigned char*)mask, flag, ctx);
    // output projection: [8192,1024] x [1024,1024]^T
    {
        dim3 g(64, 8);
        k_gemm<1><<<g, 256, 0, stream>>>(ctx, wot, bo, (void*)attn_out, 1024, 1024);
    }
    // FFN1 + relu: [8192,1024] x [4096,1024]^T
    {
        dim3 g(64, 32);
        k_gemm<2><<<g, 256, 0, stream>>>(attn_out, w1t, b1, (void*)hbuf, 4096, 1024);
    }
    // FFN2 -> d_out fp32: [8192,4096] x [1024,4096]^T
    {
        dim3 g(64, 8);
        k_gemm<3><<<g, 256, 0, stream>>>(hbuf, w2t, b2, d_out, 1024, 4096);
    }
}

// Round 2
// 769.929 us; speedup vs baseline: 1.5137x; 1.5137x over previous
//
#include <hip/hip_runtime.h>
#include <hip/hip_bf16.h>

// EncoderLayer: B=4,S=2048,D=1024,H=16,DH=64,DFF=4096
// Pipeline (all bf16 MFMA, fp32 accum):
//   prep(convert/transpose) -> GEMM0 qkv(+scale on Q) -> pack mask bits -> flash-attn
//   -> GEMM1 Wo -> GEMM2 W1+relu -> GEMM3 W2 -> d_out(fp32)

#define SDIM 2048
#define DDIM 1024

using floatx4 = __attribute__((ext_vector_type(4))) float;
using bf16x8  = __attribute__((ext_vector_type(8))) __bf16;
using bf16x4  = __attribute__((ext_vector_type(4))) __bf16;

// ---------------- prep kernels ----------------

__global__ void k_f2b(const float* __restrict__ in, __bf16* __restrict__ out) {
    long i = ((long)blockIdx.x * 256 + threadIdx.x) * 4;
    float4 f = *(const float4*)(in + i);
    bf16x4 v;
    v[0] = (__bf16)f.x; v[1] = (__bf16)f.y; v[2] = (__bf16)f.z; v[3] = (__bf16)f.w;
    *(bf16x4*)(out + i) = v;
}

// transpose-convert: out[c][r] = (bf16) in[r][c], R,C multiples of 32, grid=(R/32)*(C/32)
__global__ void k_tr(const float* __restrict__ in, __bf16* __restrict__ out, int R, int C) {
    __shared__ float t[32][33];
    int nrt = R >> 5;
    int tr = blockIdx.x % nrt, tc = blockIdx.x / nrt;
    int r0 = tr * 32, c0 = tc * 32;
    int lx = threadIdx.x & 31, ly = threadIdx.x >> 5; // 32x8
    #pragma unroll
    for (int i = 0; i < 32; i += 8) t[ly + i][lx] = in[(long)(r0 + ly + i) * C + c0 + lx];
    __syncthreads();
    #pragma unroll
    for (int i = 0; i < 32; i += 8) out[(long)(c0 + ly + i) * R + r0 + lx] = (__bf16)t[lx][ly + i];
}

// pack Wq/Wk/Wv [16][1024][64] -> Wqkvt[n=(which*1024+h*64+dh)][d=1024] bf16
__global__ void k_pack_qkvw(const float* __restrict__ Wq, const float* __restrict__ Wk,
                            const float* __restrict__ Wv, __bf16* __restrict__ out) {
    int bid = blockIdx.x;
    int dht = bid & 1;
    int dt = (bid >> 1) & 31;
    int h = (bid >> 6) & 15;
    int which = bid >> 10;
    const float* W = (which == 0) ? Wq : (which == 1) ? Wk : Wv;
    __shared__ float t[32][33];
    int lx = threadIdx.x & 31, ly = threadIdx.x >> 5;
    const float* src = W + ((long)h * 1024 + dt * 32) * 64 + dht * 32;
    #pragma unroll
    for (int i = 0; i < 32; i += 8) t[ly + i][lx] = src[(ly + i) * 64 + lx];
    __syncthreads();
    __bf16* dst = out + ((long)(which * 1024 + h * 64 + dht * 32)) * 1024 + dt * 32;
    #pragma unroll
    for (int i = 0; i < 32; i += 8) dst[(long)(ly + i) * 1024 + lx] = (__bf16)t[lx][ly + i];
}

__global__ void k_pack_qkvb(const float* bq, const float* bk, const float* bv, float* out) {
    int i = blockIdx.x * 256 + threadIdx.x;
    if (i < 3072) {
        int which = i >> 10, r = i & 1023;
        const float* s = (which == 0) ? bq : (which == 1) ? bk : bv;
        out[i] = s[r];
    }
}

// mask storage probe: flag=1 -> 4-byte records (int32/float), flag=0 -> 1-byte records
__global__ void k_probe(const unsigned* __restrict__ m, int* flag) {
    __shared__ int bad;
    if (threadIdx.x == 0) bad = 0;
    __syncthreads();
    int local = 0;
    for (int i = 0; i < 64; i++) {
        unsigned w = m[threadIdx.x + 256 * i];
        if (w != 0u && w != 1u && w != 0x3f800000u) local = 1;
    }
    if (local) atomicOr(&bad, 1);
    __syncthreads();
    if (threadIdx.x == 0) *flag = bad ? 0 : 1;
}

// pack mask -> 1 bit per element via wave ballot. grid = B*S*S/64 waves = 65536 blocks of 256.
__global__ void k_pack_mask(const void* __restrict__ mask, const int* __restrict__ flag,
                            unsigned long long* __restrict__ bits) {
    long wid = ((long)blockIdx.x * 256 + threadIdx.x) >> 6;
    int lane = threadIdx.x & 63;
    long e = wid * 64 + lane;
    bool pred;
    if (*flag) pred = ((const unsigned*)mask)[e] != 0u;
    else       pred = ((const unsigned char*)mask)[e] != 0;
    unsigned long long bal = __ballot(pred);
    if (lane == 0) bits[wid] = bal;
}

// ---------------- GEMM: C[M,N] = A[M,K] @ Bt[N,K]^T + bias, epilogue by MODE ----------------
// MODE 0: scatter to Q/K/Vt (N=3072); Q scaled by 1/sqrt(S). MODE 1: bf16. MODE 2: relu+bf16. MODE 3: fp32.
#define QSZ 8388608L

template <int MODE>
__global__ __launch_bounds__(256, 2) void k_gemm(const __bf16* __restrict__ A,
                                                 const __bf16* __restrict__ Bt,
                                                 const float* __restrict__ bias,
                                                 void* __restrict__ Cout, int Ndim, int K) {
    __shared__ __align__(16) __bf16 As[128][40];
    __shared__ __align__(16) __bf16 Bs[128][40];
    const int tid = threadIdx.x;
    const int wave = tid >> 6, lane = tid & 63;
    const int q = lane >> 4, l16 = lane & 15;
    const int wr = wave >> 1, wc = wave & 1;
    const long bm = (long)blockIdx.x * 128;
    const long bn = (long)blockIdx.y * 128;
    floatx4 acc[4][4] = {};

    const int srow0 = tid >> 2;
    const int sc8 = (tid & 3) * 8;

    for (int k0 = 0; k0 < K; k0 += 32) {
        __syncthreads();
        #pragma unroll
        for (int i = 0; i < 2; i++) {
            int row = srow0 + i * 64;
            *(bf16x8*)&As[row][sc8] = *(const bf16x8*)&A[(bm + row) * K + k0 + sc8];
            *(bf16x8*)&Bs[row][sc8] = *(const bf16x8*)&Bt[(bn + row) * K + k0 + sc8];
        }
        __syncthreads();
        bf16x8 af[4], bfr[4];
        #pragma unroll
        for (int i = 0; i < 4; i++) af[i] = *(const bf16x8*)&As[wr * 64 + i * 16 + l16][q * 8];
        #pragma unroll
        for (int j = 0; j < 4; j++) bfr[j] = *(const bf16x8*)&Bs[wc * 64 + j * 16 + l16][q * 8];
        #pragma unroll
        for (int i = 0; i < 4; i++)
            #pragma unroll
            for (int j = 0; j < 4; j++)
                acc[i][j] = __builtin_amdgcn_mfma_f32_16x16x32_bf16(af[i], bfr[j], acc[i][j], 0, 0, 0);
    }

    const int mrow0 = (int)bm + wr * 64 + q * 4;
    const int ncol0 = (int)bn + wc * 64;
    #pragma unroll
    for (int j = 0; j < 4; j++) {
        int nbase = ncol0 + j * 16 + l16;
        float bv = bias[nbase];
        #pragma unroll
        for (int i = 0; i < 4; i++) {
            #pragma unroll
            for (int r = 0; r < 4; r++) {
                int mm = mrow0 + i * 16 + r;
                float v = acc[i][j][r] + bv;
                if (MODE == 2) v = fmaxf(v, 0.f);
                if (MODE == 3) {
                    ((float*)Cout)[(long)mm * Ndim + nbase] = v;
                } else if (MODE == 0) {
                    int which = nbase >> 10, rem = nbase & 1023;
                    int hh = rem >> 6, dh = rem & 63;
                    int bb = mm >> 11, ss = mm & 2047;
                    long pr = (long)(bb * 16 + hh);
                    __bf16* o = (__bf16*)Cout;
                    if (which == 0) {
                        v *= 0.02209708691207961f; // 1/sqrt(2048) folded into Q
                        o[(pr * 2048 + ss) * 64 + dh] = (__bf16)v;
                    } else if (which == 1) o[QSZ + (pr * 2048 + ss) * 64 + dh] = (__bf16)v;
                    else o[2 * QSZ + (pr * 64 + dh) * 2048 + ss] = (__bf16)v;
                } else {
                    ((__bf16*)Cout)[(long)mm * Ndim + nbase] = (__bf16)v;
                }
            }
        }
    }
}

// ---------------- flash attention ----------------
// grid = 64 pairs * 32 q-tiles = 2048 blocks, 256 threads (4 waves, 16 q-rows each)
__global__ __launch_bounds__(256, 2) void k_attn(const __bf16* __restrict__ Q,
                                                 const __bf16* __restrict__ Kb,
                                                 const __bf16* __restrict__ Vt,
                                                 const unsigned* __restrict__ bitw,
                                                 __bf16* __restrict__ ctx) {
    __shared__ __align__(16) __bf16 Qs[64][72];
    __shared__ __align__(16) __bf16 Ks[128][72];
    __shared__ __align__(16) __bf16 Vts[64][136];
    __shared__ __align__(16) __bf16 Ps[4][16][136];
    __shared__ unsigned Ms[64][4];
    const int tid = threadIdx.x, wave = tid >> 6, lane = tid & 63;
    const int q = lane >> 4, l16 = lane & 15;
    const int pair = blockIdx.x >> 5, qt = blockIdx.x & 31;
    const int b = pair >> 4, h = pair & 15;

    const __bf16* Qp = Q + ((long)pair * SDIM + qt * 64) * 64;
    #pragma unroll
    for (int i = 0; i < 2; i++) {
        int v = tid + i * 256;
        int r = v >> 3, c = (v & 7) * 8;
        *(bf16x8*)&Qs[r][c] = *(const bf16x8*)&Qp[r * 64 + c];
    }

    float mrun[4], lrun[4];
    floatx4 o[4];
    #pragma unroll
    for (int r = 0; r < 4; r++) { mrun[r] = -INFINITY; lrun[r] = 0.f; }
    #pragma unroll
    for (int d = 0; d < 4; d++) o[d] = (floatx4){0.f, 0.f, 0.f, 0.f};

    const int lrow0 = wave * 16 + q * 4;               // local q-row of this lane's first acc row
    const long mrow_base = ((long)b * SDIM + qt * 64); // global mask row of local row 0

    for (int kt = 0; kt < 16; kt++) {
        __syncthreads();
        const __bf16* Kp = Kb + ((long)pair * SDIM + kt * 128) * 64;
        #pragma unroll
        for (int i = 0; i < 4; i++) {
            int v = tid + i * 256;
            int r = v >> 3, c = (v & 7) * 8;
            *(bf16x8*)&Ks[r][c] = *(const bf16x8*)&Kp[r * 64 + c];
        }
        const __bf16* Vp = Vt + (long)pair * 64 * SDIM + kt * 128;
        #pragma unroll
        for (int i = 0; i < 4; i++) {
            int v = tid + i * 256;
            int r = v >> 4, c = (v & 15) * 8;
            *(bf16x8*)&Vts[r][c] = *(const bf16x8*)&Vp[(long)r * SDIM + c];
        }
        {   // mask bits for this 64x128 tile: 64 rows x 4 words
            int mr = tid >> 2, mw = tid & 3;
            Ms[mr][mw] = bitw[((mrow_base + mr) << 6) + kt * 4 + mw];
        }
        __syncthreads();

        // S = Q K^T  (Q pre-scaled by 1/sqrt(S))
        bf16x8 a0 = *(const bf16x8*)&Qs[wave * 16 + l16][q * 8];
        bf16x8 a1 = *(const bf16x8*)&Qs[wave * 16 + l16][32 + q * 8];
        floatx4 s[8];
        #pragma unroll
        for (int ct = 0; ct < 8; ct++) {
            bf16x8 b0 = *(const bf16x8*)&Ks[ct * 16 + l16][q * 8];
            bf16x8 b1 = *(const bf16x8*)&Ks[ct * 16 + l16][32 + q * 8];
            floatx4 z = {};
            z = __builtin_amdgcn_mfma_f32_16x16x32_bf16(a0, b0, z, 0, 0, 0);
            z = __builtin_amdgcn_mfma_f32_16x16x32_bf16(a1, b1, z, 0, 0, 0);
            s[ct] = z;
        }
        // mask from LDS bitwords (broadcast reads)
        #pragma unroll
        for (int r = 0; r < 4; r++) {
            int lr = lrow0 + r;
            unsigned mm0 = Ms[lr][0], mm1 = Ms[lr][1], mm2 = Ms[lr][2], mm3 = Ms[lr][3];
            unsigned mmw[4] = {mm0, mm1, mm2, mm3};
            #pragma unroll
            for (int ct = 0; ct < 8; ct++) {
                unsigned wd = mmw[ct >> 1];
                if ((wd >> (((ct & 1) << 4) + l16)) & 1u) s[ct][r] = -1e9f;
            }
        }
        // row max (across 8 col-tiles then 16-lane group)
        float mnew[4], alpha[4];
        #pragma unroll
        for (int r = 0; r < 4; r++) {
            float v = s[0][r];
            #pragma unroll
            for (int ct = 1; ct < 8; ct++) v = fmaxf(v, s[ct][r]);
            #pragma unroll
            for (int off = 1; off < 16; off <<= 1) v = fmaxf(v, __shfl_xor(v, off));
            mnew[r] = fmaxf(mrun[r], v);
            alpha[r] = __expf(mrun[r] - mnew[r]);
            mrun[r] = mnew[r];
        }
        // p = exp(s - m), row sum
        float rs[4] = {0.f, 0.f, 0.f, 0.f};
        #pragma unroll
        for (int ct = 0; ct < 8; ct++)
            #pragma unroll
            for (int r = 0; r < 4; r++) {
                float p = __expf(s[ct][r] - mnew[r]);
                s[ct][r] = p;
                rs[r] += p;
            }
        #pragma unroll
        for (int r = 0; r < 4; r++) {
            float v = rs[r];
            #pragma unroll
            for (int off = 1; off < 16; off <<= 1) v += __shfl_xor(v, off);
            lrun[r] = lrun[r] * alpha[r] + v;
        }
        #pragma unroll
        for (int d = 0; d < 4; d++)
            #pragma unroll
            for (int r = 0; r < 4; r++) o[d][r] *= alpha[r];
        // P -> LDS (C-layout -> A-layout transform)
        #pragma unroll
        for (int ct = 0; ct < 8; ct++)
            #pragma unroll
            for (int r = 0; r < 4; r++)
                Ps[wave][q * 4 + r][ct * 16 + l16] = (__bf16)s[ct][r];
        __syncthreads();
        // O += P V
        #pragma unroll
        for (int kk = 0; kk < 4; kk++) {
            bf16x8 ap = *(const bf16x8*)&Ps[wave][l16][kk * 32 + q * 8];
            #pragma unroll
            for (int d = 0; d < 4; d++) {
                bf16x8 bv = *(const bf16x8*)&Vts[d * 16 + l16][kk * 32 + q * 8];
                o[d] = __builtin_amdgcn_mfma_f32_16x16x32_bf16(ap, bv, o[d], 0, 0, 0);
            }
        }
    }
    // epilogue: ctx[b][s][h*64+dh] = o / l
    #pragma unroll
    for (int r = 0; r < 4; r++) {
        float inv = 1.0f / lrun[r];
        int row = qt * 64 + lrow0 + r;
        long base = ((long)b * SDIM + row) * DDIM + h * 64;
        #pragma unroll
        for (int d = 0; d < 4; d++) ctx[base + d * 16 + l16] = (__bf16)(o[d][r] * inv);
    }
}

// ---------------- launch ----------------

extern "C" void kernel_launch(void* const* d_in, const int* in_sizes, int n_in,
                              void* d_out, int out_size, void* d_ws, size_t ws_size,
                              hipStream_t stream) {
    const float* x = (const float*)d_in[0];
    const void* mask = d_in[1];
    const float* Wq = (const float*)d_in[2];
    const float* bq = (const float*)d_in[3];
    const float* Wk = (const float*)d_in[4];
    const float* bk = (const float*)d_in[5];
    const float* Wv = (const float*)d_in[6];
    const float* bv = (const float*)d_in[7];
    const float* Wo = (const float*)d_in[8];
    const float* bo = (const float*)d_in[9];
    const float* W1 = (const float*)d_in[10];
    const float* b1 = (const float*)d_in[11];
    const float* W2 = (const float*)d_in[12];
    const float* b2 = (const float*)d_in[13];

    char* ws = (char*)d_ws;
    __bf16* xb   = (__bf16*)(ws + 0);          // 16 MB; aliased as ctx after GEMM0
    __bf16* Qb   = (__bf16*)(ws + 16777216);   // 16 MB; aliased as attn_out after attention
    __bf16* Kb   = (__bf16*)(ws + 33554432);   // 16 MB
    __bf16* Vtb  = (__bf16*)(ws + 50331648);   // 16 MB
    __bf16* hbuf = (__bf16*)(ws + 33554432);   // 64 MB (aliases K,Vt after attention)
    __bf16* wqkvt = (__bf16*)(ws + 100663296); // 6 MB; aliased as mask-bits after GEMM0
    __bf16* wot  = (__bf16*)(ws + 106954752);  // 2 MB
    __bf16* w1t  = (__bf16*)(ws + 109051904);  // 8 MB
    __bf16* w2t  = (__bf16*)(ws + 117440512);  // 8 MB
    float* bqkv  = (float*)(ws + 125829120);   // 12 KB
    int* flag    = (int*)(ws + 125841408);     // 4 B
    __bf16* ctx = xb;
    __bf16* attn_out = Qb;
    unsigned long long* bits = (unsigned long long*)wqkvt; // 2 MB, live after GEMM0

    // prep
    k_f2b<<<8192, 256, 0, stream>>>(x, xb);
    k_pack_qkvw<<<3072, 256, 0, stream>>>(Wq, Wk, Wv, wqkvt);
    k_pack_qkvb<<<12, 256, 0, stream>>>(bq, bk, bv, bqkv);
    k_tr<<<1024, 256, 0, stream>>>(Wo, wot, 1024, 1024);
    k_tr<<<4096, 256, 0, stream>>>(W1, w1t, 1024, 4096);
    k_tr<<<4096, 256, 0, stream>>>(W2, w2t, 4096, 1024);
    k_probe<<<1, 256, 0, stream>>>((const unsigned*)mask, flag);

    // QKV projection: [8192,1024] x [3072,1024]^T
    {
        dim3 g(64, 24);
        k_gemm<0><<<g, 256, 0, stream>>>(xb, wqkvt, bqkv, (void*)Qb, 3072, 1024);
    }
    // mask -> bits (reuses wqkvt space; stream-ordered after GEMM0)
    k_pack_mask<<<65536, 256, 0, stream>>>(mask, flag, bits);
    // attention
    k_attn<<<2048, 256, 0, stream>>>(Qb, Kb, Vtb, (const unsigned*)bits, ctx);
    // output projection: [8192,1024] x [1024,1024]^T
    {
        dim3 g(64, 8);
        k_gemm<1><<<g, 256, 0, stream>>>(ctx, wot, bo, (void*)attn_out, 1024, 1024);
    }
    // FFN1 + relu: [8192,1024] x [4096,1024]^T
    {
        dim3 g(64, 32);
        k_gemm<2><<<g, 256, 0, stream>>>(attn_out, w1t, b1, (void*)hbuf, 4096, 1024);
    }
    // FFN2 -> d_out fp32: [8192,4096] x [1024,4096]^T
    {
        dim3 g(64, 8);
        k_gemm<3><<<g, 256, 0, stream>>>(hbuf, w2t, b2, d_out, 1024, 4096);
    }
}

// Round 3
// 731.799 us; speedup vs baseline: 1.5925x; 1.0521x over previous
//
#include <hip/hip_runtime.h>
#include <hip/hip_bf16.h>

// EncoderLayer: B=4,S=2048,D=1024,H=16,DH=64,DFF=4096
// prep -> GEMM0 qkv(+Q scale) -> mask bits -> flash-attn (S^T form) -> GEMM1 Wo -> GEMM2 W1+relu -> GEMM3 W2

#define SDIM 2048
#define DDIM 1024

using floatx4 = __attribute__((ext_vector_type(4))) float;
using bf16x8  = __attribute__((ext_vector_type(8))) __bf16;
using bf16x4  = __attribute__((ext_vector_type(4))) __bf16;
using short4v = __attribute__((ext_vector_type(4))) short;

// global -> LDS direct copy, 16B per lane; lptr must be wave-uniform (HW adds lane*16)
#define GLDS16(gptr, lptr)                                                        \
    __builtin_amdgcn_global_load_lds(                                             \
        (const __attribute__((address_space(1))) void*)(uintptr_t)(gptr),         \
        (__attribute__((address_space(3))) void*)(uintptr_t)(lptr), 16, 0, 0)

// ---------------- prep kernels ----------------

__global__ void k_f2b(const float* __restrict__ in, __bf16* __restrict__ out) {
    long i = ((long)blockIdx.x * 256 + threadIdx.x) * 4;
    float4 f = *(const float4*)(in + i);
    bf16x4 v;
    v[0] = (__bf16)f.x; v[1] = (__bf16)f.y; v[2] = (__bf16)f.z; v[3] = (__bf16)f.w;
    *(bf16x4*)(out + i) = v;
}

__global__ void k_tr(const float* __restrict__ in, __bf16* __restrict__ out, int R, int C) {
    __shared__ float t[32][33];
    int nrt = R >> 5;
    int tr = blockIdx.x % nrt, tc = blockIdx.x / nrt;
    int r0 = tr * 32, c0 = tc * 32;
    int lx = threadIdx.x & 31, ly = threadIdx.x >> 5;
    #pragma unroll
    for (int i = 0; i < 32; i += 8) t[ly + i][lx] = in[(long)(r0 + ly + i) * C + c0 + lx];
    __syncthreads();
    #pragma unroll
    for (int i = 0; i < 32; i += 8) out[(long)(c0 + ly + i) * R + r0 + lx] = (__bf16)t[lx][ly + i];
}

__global__ void k_pack_qkvw(const float* __restrict__ Wq, const float* __restrict__ Wk,
                            const float* __restrict__ Wv, __bf16* __restrict__ out) {
    int bid = blockIdx.x;
    int dht = bid & 1;
    int dt = (bid >> 1) & 31;
    int h = (bid >> 6) & 15;
    int which = bid >> 10;
    const float* W = (which == 0) ? Wq : (which == 1) ? Wk : Wv;
    __shared__ float t[32][33];
    int lx = threadIdx.x & 31, ly = threadIdx.x >> 5;
    const float* src = W + ((long)h * 1024 + dt * 32) * 64 + dht * 32;
    #pragma unroll
    for (int i = 0; i < 32; i += 8) t[ly + i][lx] = src[(ly + i) * 64 + lx];
    __syncthreads();
    __bf16* dst = out + ((long)(which * 1024 + h * 64 + dht * 32)) * 1024 + dt * 32;
    #pragma unroll
    for (int i = 0; i < 32; i += 8) dst[(long)(ly + i) * 1024 + lx] = (__bf16)t[lx][ly + i];
}

__global__ void k_pack_qkvb(const float* bq, const float* bk, const float* bv, float* out) {
    int i = blockIdx.x * 256 + threadIdx.x;
    if (i < 3072) {
        int which = i >> 10, r = i & 1023;
        const float* s = (which == 0) ? bq : (which == 1) ? bk : bv;
        out[i] = s[r];
    }
}

__global__ void k_probe(const unsigned* __restrict__ m, int* flag) {
    __shared__ int bad;
    if (threadIdx.x == 0) bad = 0;
    __syncthreads();
    int local = 0;
    for (int i = 0; i < 64; i++) {
        unsigned w = m[threadIdx.x + 256 * i];
        if (w != 0u && w != 1u && w != 0x3f800000u) local = 1;
    }
    if (local) atomicOr(&bad, 1);
    __syncthreads();
    if (threadIdx.x == 0) *flag = bad ? 0 : 1;
}

__global__ void k_pack_mask(const void* __restrict__ mask, const int* __restrict__ flag,
                            unsigned long long* __restrict__ bits) {
    long wid = ((long)blockIdx.x * 256 + threadIdx.x) >> 6;
    int lane = threadIdx.x & 63;
    long e = wid * 64 + lane;
    bool pred;
    if (*flag) pred = ((const unsigned*)mask)[e] != 0u;
    else       pred = ((const unsigned char*)mask)[e] != 0;
    unsigned long long bal = __ballot(pred);
    if (lane == 0) bits[wid] = bal;
}

// ---------------- GEMM (m97-style global_load_lds staging, unpadded LDS) ----------------
// MODE 0: scatter to Q/K/Vt (N=3072); Q scaled by 1/sqrt(S). MODE 1: bf16. MODE 2: relu+bf16. MODE 3: fp32.
#define QSZ 8388608L

template <int MODE>
__global__ __launch_bounds__(256, 3) void k_gemm(const __bf16* __restrict__ A,
                                                 const __bf16* __restrict__ Bt,
                                                 const float* __restrict__ bias,
                                                 void* __restrict__ Cout, int Ndim, int K) {
    __shared__ __align__(16) __bf16 As[128 * 32];
    __shared__ __align__(16) __bf16 Bs[128 * 32];
    const int tid = threadIdx.x;
    const int wave = tid >> 6, lane = tid & 63;
    const int q = lane >> 4, l16 = lane & 15;
    const int wr = wave >> 1, wc = wave & 1;
    const long bm = (long)blockIdx.x * 128;
    const long bn = (long)blockIdx.y * 128;
    floatx4 acc[4][4] = {};

    // staging geometry: per instr, wave-uniform LDS base; lane covers base+lane*16
    const int srow = (lane >> 2);           // + wave*16 + i*64
    const int scol = (lane & 3) * 8;

    for (int k0 = 0; k0 < K; k0 += 32) {
        __syncthreads();
        #pragma unroll
        for (int i = 0; i < 2; i++) {
            int row = wave * 16 + i * 64 + srow;
            GLDS16(&A[(bm + row) * K + k0 + scol], (char*)As + wave * 1024 + i * 4096);
            GLDS16(&Bt[(bn + row) * K + k0 + scol], (char*)Bs + wave * 1024 + i * 4096);
        }
        __syncthreads();
        bf16x8 af[4], bfr[4];
        #pragma unroll
        for (int i = 0; i < 4; i++) af[i] = *(const bf16x8*)&As[(wr * 64 + i * 16 + l16) * 32 + q * 8];
        #pragma unroll
        for (int j = 0; j < 4; j++) bfr[j] = *(const bf16x8*)&Bs[(wc * 64 + j * 16 + l16) * 32 + q * 8];
        #pragma unroll
        for (int i = 0; i < 4; i++)
            #pragma unroll
            for (int j = 0; j < 4; j++)
                acc[i][j] = __builtin_amdgcn_mfma_f32_16x16x32_bf16(af[i], bfr[j], acc[i][j], 0, 0, 0);
    }

    const int mrow0 = (int)bm + wr * 64 + q * 4;
    const int ncol0 = (int)bn + wc * 64;
    #pragma unroll
    for (int j = 0; j < 4; j++) {
        int nbase = ncol0 + j * 16 + l16;
        float bv = bias[nbase];
        #pragma unroll
        for (int i = 0; i < 4; i++) {
            #pragma unroll
            for (int r = 0; r < 4; r++) {
                int mm = mrow0 + i * 16 + r;
                float v = acc[i][j][r] + bv;
                if (MODE == 2) v = fmaxf(v, 0.f);
                if (MODE == 3) {
                    ((float*)Cout)[(long)mm * Ndim + nbase] = v;
                } else if (MODE == 0) {
                    int which = nbase >> 10, rem = nbase & 1023;
                    int hh = rem >> 6, dh = rem & 63;
                    int bb = mm >> 11, ss = mm & 2047;
                    long pr = (long)(bb * 16 + hh);
                    __bf16* o = (__bf16*)Cout;
                    if (which == 0) {
                        v *= 0.02209708691207961f; // 1/sqrt(2048) folded into Q
                        o[(pr * 2048 + ss) * 64 + dh] = (__bf16)v;
                    } else if (which == 1) o[QSZ + (pr * 2048 + ss) * 64 + dh] = (__bf16)v;
                    else o[2 * QSZ + (pr * 64 + dh) * 2048 + ss] = (__bf16)v;
                } else {
                    ((__bf16*)Cout)[(long)mm * Ndim + nbase] = (__bf16)v;
                }
            }
        }
    }
}

// ---------------- flash attention (S^T form) ----------------
// grid = 64 pairs * 32 q-tiles; 256 threads = 4 waves, each wave owns 16 q-rows (qrow = l16).
// S^T = K·Q^T via 16x16x32 (C-layout: col=qrow, row=kcol) -> per-lane scalar softmax state;
// PV:  O^T = V^T·P^T via 16x16x16bf16_1k, B-frag (k=quad*4+j) == S^T C-layout -> P stays in regs.
__global__ __launch_bounds__(256, 3) void k_attn(const __bf16* __restrict__ Q,
                                                 const __bf16* __restrict__ Kb,
                                                 const __bf16* __restrict__ Vt,
                                                 const unsigned* __restrict__ bitw,
                                                 __bf16* __restrict__ ctx) {
    __shared__ __align__(16) __bf16 Qs[64][72];
    __shared__ __align__(16) __bf16 Ks[128][72];
    __shared__ __align__(16) __bf16 Vts[64][136];
    __shared__ unsigned Ms[64][4];
    const int tid = threadIdx.x, wave = tid >> 6, lane = tid & 63;
    const int q = lane >> 4, l16 = lane & 15;
    const int pair = blockIdx.x >> 5, qt = blockIdx.x & 31;
    const int b = pair >> 4, h = pair & 15;

    const __bf16* Qp = Q + ((long)pair * SDIM + qt * 64) * 64;
    #pragma unroll
    for (int i = 0; i < 2; i++) {
        int v = tid + i * 256;
        int r = v >> 3, c = (v & 7) * 8;
        *(bf16x8*)&Qs[r][c] = *(const bf16x8*)&Qp[r * 64 + c];
    }
    __syncthreads();
    // hoisted Q B-fragments: this wave's 16 q-rows
    const bf16x8 qf0 = *(const bf16x8*)&Qs[wave * 16 + l16][q * 8];
    const bf16x8 qf1 = *(const bf16x8*)&Qs[wave * 16 + l16][32 + q * 8];

    float mrun = -INFINITY, lrun = 0.f;
    floatx4 o[4] = {};

    const long mrow0 = (long)b * SDIM + qt * 64;

    for (int kt = 0; kt < 16; kt++) {
        __syncthreads();
        const __bf16* Kp = Kb + ((long)pair * SDIM + kt * 128) * 64;
        #pragma unroll
        for (int i = 0; i < 4; i++) {
            int v = tid + i * 256;
            int r = v >> 3, c = (v & 7) * 8;
            *(bf16x8*)&Ks[r][c] = *(const bf16x8*)&Kp[r * 64 + c];
        }
        const __bf16* Vp = Vt + (long)pair * 64 * SDIM + kt * 128;
        #pragma unroll
        for (int i = 0; i < 4; i++) {
            int v = tid + i * 256;
            int r = v >> 4, c = (v & 15) * 8;
            *(bf16x8*)&Vts[r][c] = *(const bf16x8*)&Vp[(long)r * SDIM + c];
        }
        {
            int mr = tid >> 2, mw = tid & 3;
            Ms[mr][mw] = bitw[((mrow0 + mr) << 6) + kt * 4 + mw];
        }
        __syncthreads();

        // S^T: rows = kcol (q*4+r within ct tile), col = qrow (l16)
        floatx4 st[8];
        #pragma unroll
        for (int ct = 0; ct < 8; ct++) {
            bf16x8 kf0 = *(const bf16x8*)&Ks[ct * 16 + l16][q * 8];
            bf16x8 kf1 = *(const bf16x8*)&Ks[ct * 16 + l16][32 + q * 8];
            floatx4 z = {};
            z = __builtin_amdgcn_mfma_f32_16x16x32_bf16(kf0, qf0, z, 0, 0, 0);
            z = __builtin_amdgcn_mfma_f32_16x16x32_bf16(kf1, qf1, z, 0, 0, 0);
            st[ct] = z;
        }
        // mask: this lane's q-row bits (broadcast across the 4 q-lanes)
        {
            const int lr = wave * 16 + l16;
            unsigned w0 = Ms[lr][0], w1 = Ms[lr][1], w2 = Ms[lr][2], w3 = Ms[lr][3];
            unsigned mwv[4] = {w0, w1, w2, w3};
            #pragma unroll
            for (int ct = 0; ct < 8; ct++) {
                unsigned wd = mwv[ct >> 1];
                int bp = ((ct & 1) << 4) + q * 4;
                #pragma unroll
                for (int r = 0; r < 4; r++)
                    if ((wd >> (bp + r)) & 1u) st[ct][r] = -1e9f;
            }
        }
        // tile max over this lane's 32 kcols, then across q (lanes xor 16,32)
        float tm = st[0][0];
        #pragma unroll
        for (int ct = 0; ct < 8; ct++)
            #pragma unroll
            for (int r = 0; r < 4; r++) tm = fmaxf(tm, st[ct][r]);
        tm = fmaxf(tm, __shfl_xor(tm, 16));
        tm = fmaxf(tm, __shfl_xor(tm, 32));
        float mnew = fmaxf(mrun, tm);
        float alpha = __expf(mrun - mnew);
        mrun = mnew;
        // p = exp(s - m), row sum
        float rsum = 0.f;
        #pragma unroll
        for (int ct = 0; ct < 8; ct++)
            #pragma unroll
            for (int r = 0; r < 4; r++) {
                float p = __expf(st[ct][r] - mnew);
                st[ct][r] = p;
                rsum += p;
            }
        rsum += __shfl_xor(rsum, 16);
        rsum += __shfl_xor(rsum, 32);
        lrun = lrun * alpha + rsum;
        #pragma unroll
        for (int d = 0; d < 4; d++)
            #pragma unroll
            for (int r = 0; r < 4; r++) o[d][r] *= alpha;
        // O^T += V^T · P^T : A = Vts slice (m=dh, k=q*4+j), B = st regs (n=qrow, k=q*4+j)
        #pragma unroll
        for (int ct = 0; ct < 8; ct++) {
            union { bf16x4 b; short4v s; } pu;
            #pragma unroll
            for (int r = 0; r < 4; r++) pu.b[r] = (__bf16)st[ct][r];
            #pragma unroll
            for (int d = 0; d < 4; d++) {
                union { bf16x4 b; short4v s; } vu;
                vu.b = *(const bf16x4*)&Vts[d * 16 + l16][ct * 16 + q * 4];
                o[d] = __builtin_amdgcn_mfma_f32_16x16x16bf16_1k(vu.s, pu.s, o[d], 0, 0, 0);
            }
        }
    }
    // epilogue: O^T C-layout -> ctx[b][qrow][h*64 + dh], dh = d*16 + q*4 + r (4 consecutive)
    float inv = 1.0f / lrun;
    int rowg = qt * 64 + wave * 16 + l16;
    long base = ((long)b * SDIM + rowg) * DDIM + h * 64;
    #pragma unroll
    for (int d = 0; d < 4; d++) {
        bf16x4 w;
        #pragma unroll
        for (int r = 0; r < 4; r++) w[r] = (__bf16)(o[d][r] * inv);
        *(bf16x4*)&ctx[base + d * 16 + q * 4] = w;
    }
}

// ---------------- launch ----------------

extern "C" void kernel_launch(void* const* d_in, const int* in_sizes, int n_in,
                              void* d_out, int out_size, void* d_ws, size_t ws_size,
                              hipStream_t stream) {
    const float* x = (const float*)d_in[0];
    const void* mask = d_in[1];
    const float* Wq = (const float*)d_in[2];
    const float* bq = (const float*)d_in[3];
    const float* Wk = (const float*)d_in[4];
    const float* bk = (const float*)d_in[5];
    const float* Wv = (const float*)d_in[6];
    const float* bv = (const float*)d_in[7];
    const float* Wo = (const float*)d_in[8];
    const float* bo = (const float*)d_in[9];
    const float* W1 = (const float*)d_in[10];
    const float* b1 = (const float*)d_in[11];
    const float* W2 = (const float*)d_in[12];
    const float* b2 = (const float*)d_in[13];

    char* ws = (char*)d_ws;
    __bf16* xb   = (__bf16*)(ws + 0);          // 16 MB; aliased as ctx after GEMM0
    __bf16* Qb   = (__bf16*)(ws + 16777216);   // 16 MB; aliased as attn_out after attention
    __bf16* Kb   = (__bf16*)(ws + 33554432);   // 16 MB
    __bf16* Vtb  = (__bf16*)(ws + 50331648);   // 16 MB
    __bf16* hbuf = (__bf16*)(ws + 33554432);   // 64 MB (aliases K,Vt after attention)
    __bf16* wqkvt = (__bf16*)(ws + 100663296); // 6 MB; aliased as mask-bits after GEMM0
    __bf16* wot  = (__bf16*)(ws + 106954752);  // 2 MB
    __bf16* w1t  = (__bf16*)(ws + 109051904);  // 8 MB
    __bf16* w2t  = (__bf16*)(ws + 117440512);  // 8 MB
    float* bqkv  = (float*)(ws + 125829120);   // 12 KB
    int* flag    = (int*)(ws + 125841408);     // 4 B
    __bf16* ctx = xb;
    __bf16* attn_out = Qb;
    unsigned long long* bits = (unsigned long long*)wqkvt; // 2 MB, live after GEMM0

    k_f2b<<<8192, 256, 0, stream>>>(x, xb);
    k_pack_qkvw<<<3072, 256, 0, stream>>>(Wq, Wk, Wv, wqkvt);
    k_pack_qkvb<<<12, 256, 0, stream>>>(bq, bk, bv, bqkv);
    k_tr<<<1024, 256, 0, stream>>>(Wo, wot, 1024, 1024);
    k_tr<<<4096, 256, 0, stream>>>(W1, w1t, 1024, 4096);
    k_tr<<<4096, 256, 0, stream>>>(W2, w2t, 4096, 1024);
    k_probe<<<1, 256, 0, stream>>>((const unsigned*)mask, flag);

    {   // QKV projection: [8192,1024] x [3072,1024]^T
        dim3 g(64, 24);
        k_gemm<0><<<g, 256, 0, stream>>>(xb, wqkvt, bqkv, (void*)Qb, 3072, 1024);
    }
    k_pack_mask<<<65536, 256, 0, stream>>>(mask, flag, bits);
    k_attn<<<2048, 256, 0, stream>>>(Qb, Kb, Vtb, (const unsigned*)bits, ctx);
    {   // output projection
        dim3 g(64, 8);
        k_gemm<1><<<g, 256, 0, stream>>>(ctx, wot, bo, (void*)attn_out, 1024, 1024);
    }
    {   // FFN1 + relu
        dim3 g(64, 32);
        k_gemm<2><<<g, 256, 0, stream>>>(attn_out, w1t, b1, (void*)hbuf, 4096, 1024);
    }
    {   // FFN2 -> fp32 out
        dim3 g(64, 8);
        k_gemm<3><<<g, 256, 0, stream>>>(hbuf, w2t, b2, d_out, 1024, 4096);
    }
}

// Round 4
// 723.814 us; speedup vs baseline: 1.6101x; 1.0110x over previous
//
#include <hip/hip_runtime.h>
#include <hip/hip_bf16.h>

// EncoderLayer: B=4,S=2048,D=1024,H=16,DH=64,DFF=4096
// prep -> GEMM0 qkv (Q pre-scaled by log2e/sqrt(S)) -> k_trv -> mask bits
//   -> flash-attn (S^T form, no-max softmax) -> GEMM1 Wo -> GEMM2 W1+relu -> GEMM3 W2

#define SDIM 2048
#define DDIM 1024

using floatx4 = __attribute__((ext_vector_type(4))) float;
using bf16x8  = __attribute__((ext_vector_type(8))) __bf16;
using bf16x4  = __attribute__((ext_vector_type(4))) __bf16;
using short4v = __attribute__((ext_vector_type(4))) short;

// global -> LDS direct copy, 16B per lane; lptr must be wave-uniform (HW adds lane*16)
#define GLDS16(gptr, lptr)                                                        \
    __builtin_amdgcn_global_load_lds(                                             \
        (const __attribute__((address_space(1))) void*)(uintptr_t)(gptr),         \
        (__attribute__((address_space(3))) void*)(uintptr_t)(lptr), 16, 0, 0)

// ---------------- prep kernels ----------------

__global__ void k_f2b(const float* __restrict__ in, __bf16* __restrict__ out) {
    long i = ((long)blockIdx.x * 256 + threadIdx.x) * 4;
    float4 f = *(const float4*)(in + i);
    bf16x4 v;
    v[0] = (__bf16)f.x; v[1] = (__bf16)f.y; v[2] = (__bf16)f.z; v[3] = (__bf16)f.w;
    *(bf16x4*)(out + i) = v;
}

__global__ void k_tr(const float* __restrict__ in, __bf16* __restrict__ out, int R, int C) {
    __shared__ float t[32][33];
    int nrt = R >> 5;
    int tr = blockIdx.x % nrt, tc = blockIdx.x / nrt;
    int r0 = tr * 32, c0 = tc * 32;
    int lx = threadIdx.x & 31, ly = threadIdx.x >> 5;
    #pragma unroll
    for (int i = 0; i < 32; i += 8) t[ly + i][lx] = in[(long)(r0 + ly + i) * C + c0 + lx];
    __syncthreads();
    #pragma unroll
    for (int i = 0; i < 32; i += 8) out[(long)(c0 + ly + i) * R + r0 + lx] = (__bf16)t[lx][ly + i];
}

__global__ void k_pack_qkvw(const float* __restrict__ Wq, const float* __restrict__ Wk,
                            const float* __restrict__ Wv, __bf16* __restrict__ out) {
    int bid = blockIdx.x;
    int dht = bid & 1;
    int dt = (bid >> 1) & 31;
    int h = (bid >> 6) & 15;
    int which = bid >> 10;
    const float* W = (which == 0) ? Wq : (which == 1) ? Wk : Wv;
    __shared__ float t[32][33];
    int lx = threadIdx.x & 31, ly = threadIdx.x >> 5;
    const float* src = W + ((long)h * 1024 + dt * 32) * 64 + dht * 32;
    #pragma unroll
    for (int i = 0; i < 32; i += 8) t[ly + i][lx] = src[(ly + i) * 64 + lx];
    __syncthreads();
    __bf16* dst = out + ((long)(which * 1024 + h * 64 + dht * 32)) * 1024 + dt * 32;
    #pragma unroll
    for (int i = 0; i < 32; i += 8) dst[(long)(ly + i) * 1024 + lx] = (__bf16)t[lx][ly + i];
}

__global__ void k_pack_qkvb(const float* bq, const float* bk, const float* bv, float* out) {
    int i = blockIdx.x * 256 + threadIdx.x;
    if (i < 3072) {
        int which = i >> 10, r = i & 1023;
        const float* s = (which == 0) ? bq : (which == 1) ? bk : bv;
        out[i] = s[r];
    }
}

__global__ void k_probe(const unsigned* __restrict__ m, int* flag) {
    __shared__ int bad;
    if (threadIdx.x == 0) bad = 0;
    __syncthreads();
    int local = 0;
    for (int i = 0; i < 64; i++) {
        unsigned w = m[threadIdx.x + 256 * i];
        if (w != 0u && w != 1u && w != 0x3f800000u) local = 1;
    }
    if (local) atomicOr(&bad, 1);
    __syncthreads();
    if (threadIdx.x == 0) *flag = bad ? 0 : 1;
}

__global__ void k_pack_mask(const void* __restrict__ mask, const int* __restrict__ flag,
                            unsigned long long* __restrict__ bits) {
    long wid = ((long)blockIdx.x * 256 + threadIdx.x) >> 6;
    int lane = threadIdx.x & 63;
    long e = wid * 64 + lane;
    bool pred;
    if (*flag) pred = ((const unsigned*)mask)[e] != 0u;
    else       pred = ((const unsigned char*)mask)[e] != 0;
    unsigned long long bal = __ballot(pred);
    if (lane == 0) bits[wid] = bal;
}

// V row-layout [pair][2048][64] -> Vt [pair][64][2048]; grid = 64 pairs * 64 s-tiles
__global__ void k_trv(const __bf16* __restrict__ Vrow, __bf16* __restrict__ Vt) {
    __shared__ __bf16 t[32][72];
    int p = blockIdx.x >> 6, ts = blockIdx.x & 63;
    int tid = threadIdx.x;
    const __bf16* src = Vrow + ((long)p * 2048 + ts * 32) * 64;
    int s = tid >> 3, c = (tid & 7) * 8;
    *(bf16x8*)&t[s][c] = *(const bf16x8*)&src[s * 64 + c];
    __syncthreads();
    int dh = tid >> 2, sb = (tid & 3) * 8;
    bf16x8 w;
    #pragma unroll
    for (int j = 0; j < 8; j++) w[j] = t[sb + j][dh];
    *(bf16x8*)&Vt[((long)p * 64 + dh) * 2048 + ts * 32 + sb] = w;
}

// ---------------- GEMM (m97-style global_load_lds staging, unpadded LDS) ----------------
// MODE 0: scatter to Q/K/Vrow (N=3072); Q scaled by log2e/sqrt(S). MODE 1: bf16. MODE 2: relu+bf16. MODE 3: fp32.
#define QSZ 8388608L

template <int MODE>
__global__ __launch_bounds__(256, 3) void k_gemm(const __bf16* __restrict__ A,
                                                 const __bf16* __restrict__ Bt,
                                                 const float* __restrict__ bias,
                                                 void* __restrict__ Cout, int Ndim, int K) {
    __shared__ __align__(16) __bf16 As[128 * 32];
    __shared__ __align__(16) __bf16 Bs[128 * 32];
    const int tid = threadIdx.x;
    const int wave = tid >> 6, lane = tid & 63;
    const int q = lane >> 4, l16 = lane & 15;
    const int wr = wave >> 1, wc = wave & 1;
    const long bm = (long)blockIdx.x * 128;
    const long bn = (long)blockIdx.y * 128;
    floatx4 acc[4][4] = {};

    const int srow = (lane >> 2);
    const int scol = (lane & 3) * 8;

    for (int k0 = 0; k0 < K; k0 += 32) {
        __syncthreads();
        #pragma unroll
        for (int i = 0; i < 2; i++) {
            int row = wave * 16 + i * 64 + srow;
            GLDS16(&A[(bm + row) * K + k0 + scol], (char*)As + wave * 1024 + i * 4096);
            GLDS16(&Bt[(bn + row) * K + k0 + scol], (char*)Bs + wave * 1024 + i * 4096);
        }
        __syncthreads();
        bf16x8 af[4], bfr[4];
        #pragma unroll
        for (int i = 0; i < 4; i++) af[i] = *(const bf16x8*)&As[(wr * 64 + i * 16 + l16) * 32 + q * 8];
        #pragma unroll
        for (int j = 0; j < 4; j++) bfr[j] = *(const bf16x8*)&Bs[(wc * 64 + j * 16 + l16) * 32 + q * 8];
        #pragma unroll
        for (int i = 0; i < 4; i++)
            #pragma unroll
            for (int j = 0; j < 4; j++)
                acc[i][j] = __builtin_amdgcn_mfma_f32_16x16x32_bf16(af[i], bfr[j], acc[i][j], 0, 0, 0);
    }

    const int mrow0 = (int)bm + wr * 64 + q * 4;
    const int ncol0 = (int)bn + wc * 64;
    #pragma unroll
    for (int j = 0; j < 4; j++) {
        int nbase = ncol0 + j * 16 + l16;
        float bv = bias[nbase];
        #pragma unroll
        for (int i = 0; i < 4; i++) {
            #pragma unroll
            for (int r = 0; r < 4; r++) {
                int mm = mrow0 + i * 16 + r;
                float v = acc[i][j][r] + bv;
                if (MODE == 2) v = fmaxf(v, 0.f);
                if (MODE == 3) {
                    ((float*)Cout)[(long)mm * Ndim + nbase] = v;
                } else if (MODE == 0) {
                    int which = nbase >> 10, rem = nbase & 1023;
                    int hh = rem >> 6, dh = rem & 63;
                    int bb = mm >> 11, ss = mm & 2047;
                    long pr = (long)(bb * 16 + hh);
                    __bf16* o = (__bf16*)Cout;
                    if (which == 0) {
                        v *= 0.03188152837f; // log2(e)/sqrt(2048): softmax done in exp2 domain
                        o[(pr * 2048 + ss) * 64 + dh] = (__bf16)v;
                    } else if (which == 1) o[QSZ + (pr * 2048 + ss) * 64 + dh] = (__bf16)v;
                    else o[3 * QSZ + (pr * 2048 + ss) * 64 + dh] = (__bf16)v; // V coalesced; k_trv transposes
                } else {
                    ((__bf16*)Cout)[(long)mm * Ndim + nbase] = (__bf16)v;
                }
            }
        }
    }
}

// ---------------- flash attention (S^T form, no-max softmax) ----------------
// Scores are bounded (|s| < ~1), so p = exp2(s2) directly (s2 pre-scaled by log2e/sqrt(S));
// masked -> p = 0 exactly (reference's exp(-1e9 - m) also underflows to 0).
// grid: bid&63 = pair (keeps a pair's 32 q-tiles on one XCD for K/V L2 reuse), bid>>6 = qt.
__global__ __launch_bounds__(256, 3) void k_attn(const __bf16* __restrict__ Q,
                                                 const __bf16* __restrict__ Kb,
                                                 const __bf16* __restrict__ Vt,
                                                 const unsigned* __restrict__ bitw,
                                                 __bf16* __restrict__ ctx) {
    __shared__ __align__(16) __bf16 Qs[64][72];
    __shared__ __align__(16) __bf16 Ks[128][72];
    __shared__ __align__(16) __bf16 Vts[64][136];
    __shared__ unsigned Ms[64][4];
    const int tid = threadIdx.x, wave = tid >> 6, lane = tid & 63;
    const int q = lane >> 4, l16 = lane & 15;
    const int pair = blockIdx.x & 63, qt = blockIdx.x >> 6;
    const int b = pair >> 4, h = pair & 15;

    const __bf16* Qp = Q + ((long)pair * SDIM + qt * 64) * 64;
    #pragma unroll
    for (int i = 0; i < 2; i++) {
        int v = tid + i * 256;
        int r = v >> 3, c = (v & 7) * 8;
        *(bf16x8*)&Qs[r][c] = *(const bf16x8*)&Qp[r * 64 + c];
    }
    __syncthreads();
    const bf16x8 qf0 = *(const bf16x8*)&Qs[wave * 16 + l16][q * 8];
    const bf16x8 qf1 = *(const bf16x8*)&Qs[wave * 16 + l16][32 + q * 8];

    float lacc = 0.f;
    floatx4 o[4] = {};

    const long mrow0 = (long)b * SDIM + qt * 64;

    for (int kt = 0; kt < 16; kt++) {
        __syncthreads();
        const __bf16* Kp = Kb + ((long)pair * SDIM + kt * 128) * 64;
        #pragma unroll
        for (int i = 0; i < 4; i++) {
            int v = tid + i * 256;
            int r = v >> 3, c = (v & 7) * 8;
            *(bf16x8*)&Ks[r][c] = *(const bf16x8*)&Kp[r * 64 + c];
        }
        const __bf16* Vp = Vt + (long)pair * 64 * SDIM + kt * 128;
        #pragma unroll
        for (int i = 0; i < 4; i++) {
            int v = tid + i * 256;
            int r = v >> 4, c = (v & 15) * 8;
            *(bf16x8*)&Vts[r][c] = *(const bf16x8*)&Vp[(long)r * SDIM + c];
        }
        {
            int mr = tid >> 2, mw = tid & 3;
            Ms[mr][mw] = bitw[((mrow0 + mr) << 6) + kt * 4 + mw];
        }
        __syncthreads();

        // S^T: rows = kcol, col = qrow (l16); already in exp2 domain
        floatx4 st[8];
        #pragma unroll
        for (int ct = 0; ct < 8; ct++) {
            bf16x8 kf0 = *(const bf16x8*)&Ks[ct * 16 + l16][q * 8];
            bf16x8 kf1 = *(const bf16x8*)&Ks[ct * 16 + l16][32 + q * 8];
            floatx4 z = {};
            z = __builtin_amdgcn_mfma_f32_16x16x32_bf16(kf0, qf0, z, 0, 0, 0);
            z = __builtin_amdgcn_mfma_f32_16x16x32_bf16(kf1, qf1, z, 0, 0, 0);
            st[ct] = z;
        }
        // p = exp2(s); masked -> 0; accumulate per-lane l (cross-lane reduce deferred to end)
        const int lr = wave * 16 + l16;
        unsigned w0 = Ms[lr][0], w1 = Ms[lr][1], w2 = Ms[lr][2], w3 = Ms[lr][3];
        unsigned mwv[4] = {w0, w1, w2, w3};
        #pragma unroll
        for (int ct = 0; ct < 8; ct++) {
            unsigned wd = mwv[ct >> 1];
            int bp = ((ct & 1) << 4) + q * 4;
            #pragma unroll
            for (int r = 0; r < 4; r++) {
                float p = exp2f(st[ct][r]);
                p = ((wd >> (bp + r)) & 1u) ? 0.f : p;
                st[ct][r] = p;
                lacc += p;
            }
        }
        // O^T += V^T · P^T (P straight from registers: S^T C-layout == 16x16x16 B-layout)
        #pragma unroll
        for (int ct = 0; ct < 8; ct++) {
            union { bf16x4 b; short4v s; } pu;
            #pragma unroll
            for (int r = 0; r < 4; r++) pu.b[r] = (__bf16)st[ct][r];
            #pragma unroll
            for (int d = 0; d < 4; d++) {
                union { bf16x4 b; short4v s; } vu;
                vu.b = *(const bf16x4*)&Vts[d * 16 + l16][ct * 16 + q * 4];
                o[d] = __builtin_amdgcn_mfma_f32_16x16x16bf16_1k(vu.s, pu.s, o[d], 0, 0, 0);
            }
        }
    }
    // single cross-lane l reduction (q-lanes hold disjoint kcol partials)
    lacc += __shfl_xor(lacc, 16);
    lacc += __shfl_xor(lacc, 32);
    float inv = 1.0f / lacc;
    int rowg = qt * 64 + wave * 16 + l16;
    long base = ((long)b * SDIM + rowg) * DDIM + h * 64;
    #pragma unroll
    for (int d = 0; d < 4; d++) {
        bf16x4 w;
        #pragma unroll
        for (int r = 0; r < 4; r++) w[r] = (__bf16)(o[d][r] * inv);
        *(bf16x4*)&ctx[base + d * 16 + q * 4] = w;
    }
}

// ---------------- launch ----------------

extern "C" void kernel_launch(void* const* d_in, const int* in_sizes, int n_in,
                              void* d_out, int out_size, void* d_ws, size_t ws_size,
                              hipStream_t stream) {
    const float* x = (const float*)d_in[0];
    const void* mask = d_in[1];
    const float* Wq = (const float*)d_in[2];
    const float* bq = (const float*)d_in[3];
    const float* Wk = (const float*)d_in[4];
    const float* bk = (const float*)d_in[5];
    const float* Wv = (const float*)d_in[6];
    const float* bv = (const float*)d_in[7];
    const float* Wo = (const float*)d_in[8];
    const float* bo = (const float*)d_in[9];
    const float* W1 = (const float*)d_in[10];
    const float* b1 = (const float*)d_in[11];
    const float* W2 = (const float*)d_in[12];
    const float* b2 = (const float*)d_in[13];

    char* ws = (char*)d_ws;
    __bf16* xb   = (__bf16*)(ws + 0);          // 16 MB; aliased as ctx after GEMM0
    __bf16* Qb   = (__bf16*)(ws + 16777216);   // 16 MB; aliased as attn_out after attention
    __bf16* Kb   = (__bf16*)(ws + 33554432);   // 16 MB (= Qb + QSZ)
    __bf16* Vtb  = (__bf16*)(ws + 50331648);   // 16 MB (= Qb + 2*QSZ)
    __bf16* Vrow = (__bf16*)(ws + 67108864);   // 16 MB (= Qb + 3*QSZ); dead after k_trv
    __bf16* hbuf = (__bf16*)(ws + 33554432);   // 64 MB (aliases Kb/Vtb/Vrow after attention)
    __bf16* wqkvt = (__bf16*)(ws + 100663296); // 6 MB; aliased as mask-bits after GEMM0
    __bf16* wot  = (__bf16*)(ws + 106954752);  // 2 MB
    __bf16* w1t  = (__bf16*)(ws + 109051904);  // 8 MB
    __bf16* w2t  = (__bf16*)(ws + 117440512);  // 8 MB
    float* bqkv  = (float*)(ws + 125829120);   // 12 KB
    int* flag    = (int*)(ws + 125841408);     // 4 B
    __bf16* ctx = xb;
    __bf16* attn_out = Qb;
    unsigned long long* bits = (unsigned long long*)wqkvt; // 2 MB, live after GEMM0
    (void)Vrow;

    k_f2b<<<8192, 256, 0, stream>>>(x, xb);
    k_pack_qkvw<<<3072, 256, 0, stream>>>(Wq, Wk, Wv, wqkvt);
    k_pack_qkvb<<<12, 256, 0, stream>>>(bq, bk, bv, bqkv);
    k_tr<<<1024, 256, 0, stream>>>(Wo, wot, 1024, 1024);
    k_tr<<<4096, 256, 0, stream>>>(W1, w1t, 1024, 4096);
    k_tr<<<4096, 256, 0, stream>>>(W2, w2t, 4096, 1024);
    k_probe<<<1, 256, 0, stream>>>((const unsigned*)mask, flag);

    {   // QKV projection: [8192,1024] x [3072,1024]^T; V written coalesced to Vrow
        dim3 g(64, 24);
        k_gemm<0><<<g, 256, 0, stream>>>(xb, wqkvt, bqkv, (void*)Qb, 3072, 1024);
    }
    k_trv<<<4096, 256, 0, stream>>>(Vrow, Vtb);
    k_pack_mask<<<65536, 256, 0, stream>>>(mask, flag, bits);
    k_attn<<<2048, 256, 0, stream>>>(Qb, Kb, Vtb, (const unsigned*)bits, ctx);
    {   // output projection
        dim3 g(64, 8);
        k_gemm<1><<<g, 256, 0, stream>>>(ctx, wot, bo, (void*)attn_out, 1024, 1024);
    }
    {   // FFN1 + relu
        dim3 g(64, 32);
        k_gemm<2><<<g, 256, 0, stream>>>(attn_out, w1t, b1, (void*)hbuf, 4096, 1024);
    }
    {   // FFN2 -> fp32 out
        dim3 g(64, 8);
        k_gemm<3><<<g, 256, 0, stream>>>(hbuf, w2t, b2, d_out, 1024, 4096);
    }
}

// Round 5
// 634.776 us; speedup vs baseline: 1.8360x; 1.1403x over previous
//
#include <hip/hip_runtime.h>
#include <hip/hip_bf16.h>

// EncoderLayer: B=4,S=2048,D=1024,H=16,DH=64,DFF=4096
// prep -> GEMM0 qkv (Q pre-scaled by log2e/sqrt(S)) -> k_trv -> mask bits
//   -> flash-attn (S^T form, no-max softmax, all-GLDS staging) -> GEMM1 Wo -> GEMM2 W1+relu -> GEMM3 W2
// GEMM: BK=64, unpadded LDS with XOR-rotated 16B granules (conflict-free + GLDS-compatible)

#define SDIM 2048
#define DDIM 1024

using floatx4 = __attribute__((ext_vector_type(4))) float;
using bf16x8  = __attribute__((ext_vector_type(8))) __bf16;
using bf16x4  = __attribute__((ext_vector_type(4))) __bf16;
using short4v = __attribute__((ext_vector_type(4))) short;

// global -> LDS direct copy, 16B per lane; lptr wave-uniform (HW adds lane*16)
#define GLDS16(gptr, lptr)                                                        \
    __builtin_amdgcn_global_load_lds(                                             \
        (const __attribute__((address_space(1))) void*)(uintptr_t)(gptr),         \
        (__attribute__((address_space(3))) void*)(uintptr_t)(lptr), 16, 0, 0)

// ---------------- prep kernels ----------------

__global__ void k_f2b(const float* __restrict__ in, __bf16* __restrict__ out) {
    long i = ((long)blockIdx.x * 256 + threadIdx.x) * 4;
    float4 f = *(const float4*)(in + i);
    bf16x4 v;
    v[0] = (__bf16)f.x; v[1] = (__bf16)f.y; v[2] = (__bf16)f.z; v[3] = (__bf16)f.w;
    *(bf16x4*)(out + i) = v;
}

__global__ void k_tr(const float* __restrict__ in, __bf16* __restrict__ out, int R, int C) {
    __shared__ float t[32][33];
    int nrt = R >> 5;
    int tr = blockIdx.x % nrt, tc = blockIdx.x / nrt;
    int r0 = tr * 32, c0 = tc * 32;
    int lx = threadIdx.x & 31, ly = threadIdx.x >> 5;
    #pragma unroll
    for (int i = 0; i < 32; i += 8) t[ly + i][lx] = in[(long)(r0 + ly + i) * C + c0 + lx];
    __syncthreads();
    #pragma unroll
    for (int i = 0; i < 32; i += 8) out[(long)(c0 + ly + i) * R + r0 + lx] = (__bf16)t[lx][ly + i];
}

__global__ void k_pack_qkvw(const float* __restrict__ Wq, const float* __restrict__ Wk,
                            const float* __restrict__ Wv, __bf16* __restrict__ out) {
    int bid = blockIdx.x;
    int dht = bid & 1;
    int dt = (bid >> 1) & 31;
    int h = (bid >> 6) & 15;
    int which = bid >> 10;
    const float* W = (which == 0) ? Wq : (which == 1) ? Wk : Wv;
    __shared__ float t[32][33];
    int lx = threadIdx.x & 31, ly = threadIdx.x >> 5;
    const float* src = W + ((long)h * 1024 + dt * 32) * 64 + dht * 32;
    #pragma unroll
    for (int i = 0; i < 32; i += 8) t[ly + i][lx] = src[(ly + i) * 64 + lx];
    __syncthreads();
    __bf16* dst = out + ((long)(which * 1024 + h * 64 + dht * 32)) * 1024 + dt * 32;
    #pragma unroll
    for (int i = 0; i < 32; i += 8) dst[(long)(ly + i) * 1024 + lx] = (__bf16)t[lx][ly + i];
}

__global__ void k_pack_qkvb(const float* bq, const float* bk, const float* bv, float* out) {
    int i = blockIdx.x * 256 + threadIdx.x;
    if (i < 3072) {
        int which = i >> 10, r = i & 1023;
        const float* s = (which == 0) ? bq : (which == 1) ? bk : bv;
        out[i] = s[r];
    }
}

__global__ void k_probe(const unsigned* __restrict__ m, int* flag) {
    __shared__ int bad;
    if (threadIdx.x == 0) bad = 0;
    __syncthreads();
    int local = 0;
    for (int i = 0; i < 64; i++) {
        unsigned w = m[threadIdx.x + 256 * i];
        if (w != 0u && w != 1u && w != 0x3f800000u) local = 1;
    }
    if (local) atomicOr(&bad, 1);
    __syncthreads();
    if (threadIdx.x == 0) *flag = bad ? 0 : 1;
}

__global__ void k_pack_mask(const void* __restrict__ mask, const int* __restrict__ flag,
                            unsigned long long* __restrict__ bits) {
    long wid = ((long)blockIdx.x * 256 + threadIdx.x) >> 6;
    int lane = threadIdx.x & 63;
    long e = wid * 64 + lane;
    bool pred;
    if (*flag) pred = ((const unsigned*)mask)[e] != 0u;
    else       pred = ((const unsigned char*)mask)[e] != 0;
    unsigned long long bal = __ballot(pred);
    if (lane == 0) bits[wid] = bal;
}

// V row-layout [pair][2048][64] -> Vt [pair][64][2048]
__global__ void k_trv(const __bf16* __restrict__ Vrow, __bf16* __restrict__ Vt) {
    __shared__ __bf16 t[32][72];
    int p = blockIdx.x >> 6, ts = blockIdx.x & 63;
    int tid = threadIdx.x;
    const __bf16* src = Vrow + ((long)p * 2048 + ts * 32) * 64;
    int s = tid >> 3, c = (tid & 7) * 8;
    *(bf16x8*)&t[s][c] = *(const bf16x8*)&src[s * 64 + c];
    __syncthreads();
    int dh = tid >> 2, sb = (tid & 3) * 8;
    bf16x8 w;
    #pragma unroll
    for (int j = 0; j < 8; j++) w[j] = t[sb + j][dh];
    *(bf16x8*)&Vt[((long)p * 64 + dh) * 2048 + ts * 32 + sb] = w;
}

// ---------------- GEMM: BK=64, GLDS staging, rotated granules ----------------
// MODE 0: scatter to Q/K/Vrow (N=3072); Q scaled by log2e/sqrt(S). MODE 1: bf16. MODE 2: relu+bf16. MODE 3: fp32.
#define QSZ 8388608L

template <int MODE>
__global__ __launch_bounds__(256, 3) void k_gemm(const __bf16* __restrict__ A,
                                                 const __bf16* __restrict__ Bt,
                                                 const float* __restrict__ bias,
                                                 void* __restrict__ Cout, int Ndim, int K) {
    __shared__ __align__(16) __bf16 As[128 * 64];
    __shared__ __align__(16) __bf16 Bs[128 * 64];
    const int tid = threadIdx.x;
    const int wave = tid >> 6, lane = tid & 63;
    const int q = lane >> 4, l16 = lane & 15;
    const int wr = wave >> 1, wc = wave & 1;
    const long bm = (long)blockIdx.x * 128;
    const long bn = (long)blockIdx.y * 128;
    floatx4 acc[4][4] = {};

    // staging: chunks of 8 rows x 128B; lane -> row (lane>>3), src granule ((lane&7)-(lane>>3))&7
    const int srow = lane >> 3;
    const int scol = (((lane & 7) - srow) & 7) * 8;
    const int r8 = l16 & 7; // read-side rotation

    for (int k0 = 0; k0 < K; k0 += 64) {
        __syncthreads();
        #pragma unroll
        for (int c = 0; c < 4; c++) {
            int row0 = wave * 32 + c * 8;
            GLDS16(&A[(bm + row0 + srow) * K + k0 + scol], (char*)As + row0 * 128);
            GLDS16(&Bt[(bn + row0 + srow) * K + k0 + scol], (char*)Bs + row0 * 128);
        }
        __syncthreads();
        #pragma unroll
        for (int s = 0; s < 2; s++) {
            bf16x8 af[4], bfr[4];
            #pragma unroll
            for (int i = 0; i < 4; i++)
                af[i] = *(const bf16x8*)&As[(wr * 64 + i * 16 + l16) * 64 + ((s * 4 + q + r8) & 7) * 8];
            #pragma unroll
            for (int j = 0; j < 4; j++)
                bfr[j] = *(const bf16x8*)&Bs[(wc * 64 + j * 16 + l16) * 64 + ((s * 4 + q + r8) & 7) * 8];
            #pragma unroll
            for (int i = 0; i < 4; i++)
                #pragma unroll
                for (int j = 0; j < 4; j++)
                    acc[i][j] = __builtin_amdgcn_mfma_f32_16x16x32_bf16(af[i], bfr[j], acc[i][j], 0, 0, 0);
        }
    }

    const int mrow0 = (int)bm + wr * 64 + q * 4;
    const int ncol0 = (int)bn + wc * 64;
    #pragma unroll
    for (int j = 0; j < 4; j++) {
        int nbase = ncol0 + j * 16 + l16;
        float bv = bias[nbase];
        #pragma unroll
        for (int i = 0; i < 4; i++) {
            #pragma unroll
            for (int r = 0; r < 4; r++) {
                int mm = mrow0 + i * 16 + r;
                float v = acc[i][j][r] + bv;
                if (MODE == 2) v = fmaxf(v, 0.f);
                if (MODE == 3) {
                    ((float*)Cout)[(long)mm * Ndim + nbase] = v;
                } else if (MODE == 0) {
                    int which = nbase >> 10, rem = nbase & 1023;
                    int hh = rem >> 6, dh = rem & 63;
                    int bb = mm >> 11, ss = mm & 2047;
                    long pr = (long)(bb * 16 + hh);
                    __bf16* o = (__bf16*)Cout;
                    if (which == 0) {
                        v *= 0.03188152837f; // log2(e)/sqrt(2048): softmax in exp2 domain
                        o[(pr * 2048 + ss) * 64 + dh] = (__bf16)v;
                    } else if (which == 1) o[QSZ + (pr * 2048 + ss) * 64 + dh] = (__bf16)v;
                    else o[3 * QSZ + (pr * 2048 + ss) * 64 + dh] = (__bf16)v; // V coalesced; k_trv transposes
                } else {
                    ((__bf16*)Cout)[(long)mm * Ndim + nbase] = (__bf16)v;
                }
            }
        }
    }
}

// ---------------- flash attention (S^T form, no-max softmax, all-GLDS) ----------------
// LDS = Qs 8KB + Ks 16KB + Vts 16KB = 40KB -> 4 blocks/CU.
__global__ __launch_bounds__(256, 4) void k_attn(const __bf16* __restrict__ Q,
                                                 const __bf16* __restrict__ Kb,
                                                 const __bf16* __restrict__ Vt,
                                                 const unsigned* __restrict__ bitw,
                                                 __bf16* __restrict__ ctx) {
    __shared__ __align__(16) __bf16 Qs[64 * 64];
    __shared__ __align__(16) __bf16 Ks[128 * 64];
    __shared__ __align__(16) __bf16 Vts[64 * 128];
    const int tid = threadIdx.x, wave = tid >> 6, lane = tid & 63;
    const int q = lane >> 4, l16 = lane & 15;
    const int pair = blockIdx.x & 63, qt = blockIdx.x >> 6;
    const int b = pair >> 4, h = pair & 15;

    const int srow8 = lane >> 3;                      // 8-row (128B) chunks
    const int scol8 = (((lane & 7) - srow8) & 7) * 8; // rotated source cols
    const int r8 = l16 & 7;
    const int vrow = lane >> 4;                       // 4-row (256B) chunks for V
    const int vl = lane & 15;

    // stage Q: 2 chunks/wave
    const __bf16* Qp = Q + ((long)pair * SDIM + qt * 64) * 64;
    #pragma unroll
    for (int c = 0; c < 2; c++) {
        int row0 = wave * 16 + c * 8;
        GLDS16(&Qp[(row0 + srow8) * 64 + scol8], (char*)Qs + row0 * 128);
    }
    __syncthreads();
    const bf16x8 qf0 = *(const bf16x8*)&Qs[(wave * 16 + l16) * 64 + ((q + r8) & 7) * 8];
    const bf16x8 qf1 = *(const bf16x8*)&Qs[(wave * 16 + l16) * 64 + ((q + 4 + r8) & 7) * 8];

    float lacc = 0.f;
    floatx4 o[4] = {};
    const long mrow0 = (long)b * SDIM + qt * 64;

    for (int kt = 0; kt < 16; kt++) {
        __syncthreads();
        const __bf16* Kp = Kb + ((long)pair * SDIM + kt * 128) * 64;
        #pragma unroll
        for (int c = 0; c < 4; c++) {
            int row0 = wave * 32 + c * 8;
            GLDS16(&Kp[(row0 + srow8) * 64 + scol8], (char*)Ks + row0 * 128);
        }
        const __bf16* Vp = Vt + ((long)pair * 64) * SDIM + kt * 128;
        #pragma unroll
        for (int c = 0; c < 4; c++) {
            int row0 = wave * 16 + c * 4;                       // row0 & 15 == c*4
            int gsrc = ((vl - (c * 4 + vrow)) & 15) * 8;        // mod-16 rotate (256B rows)
            GLDS16(&Vp[(long)(row0 + vrow) * SDIM + gsrc], (char*)Vts + row0 * 256);
        }
        const uint4 mq = *(const uint4*)(bitw + ((mrow0 + wave * 16 + l16) << 6) + kt * 4);
        __syncthreads();

        // S^T = K·Q^T (exp2 domain); C-layout: col = qrow (l16), row = kcol (q*4+r)
        floatx4 st[8];
        #pragma unroll
        for (int ct = 0; ct < 8; ct++) {
            bf16x8 kf0 = *(const bf16x8*)&Ks[(ct * 16 + l16) * 64 + ((q + r8) & 7) * 8];
            bf16x8 kf1 = *(const bf16x8*)&Ks[(ct * 16 + l16) * 64 + ((q + 4 + r8) & 7) * 8];
            floatx4 z = {};
            z = __builtin_amdgcn_mfma_f32_16x16x32_bf16(kf0, qf0, z, 0, 0, 0);
            z = __builtin_amdgcn_mfma_f32_16x16x32_bf16(kf1, qf1, z, 0, 0, 0);
            st[ct] = z;
        }
        // p = exp2(s); masked -> 0; per-lane l partial (reduced once at end)
        unsigned mwv[4] = {mq.x, mq.y, mq.z, mq.w};
        #pragma unroll
        for (int ct = 0; ct < 8; ct++) {
            unsigned wd = mwv[ct >> 1];
            int bp = ((ct & 1) << 4) + q * 4;
            #pragma unroll
            for (int r = 0; r < 4; r++) {
                float p = exp2f(st[ct][r]);
                p = ((wd >> (bp + r)) & 1u) ? 0.f : p;
                st[ct][r] = p;
                lacc += p;
            }
        }
        // O^T += V^T·P^T (P from regs: S^T C-layout == 16x16x16 B-layout)
        #pragma unroll
        for (int ct = 0; ct < 8; ct++) {
            union { bf16x4 b; short4v s; } pu;
            #pragma unroll
            for (int r = 0; r < 4; r++) pu.b[r] = (__bf16)st[ct][r];
            #pragma unroll
            for (int d = 0; d < 4; d++) {
                int vg = (ct * 2 + (q >> 1) + l16) & 15;
                union { bf16x4 b; short4v s; } vu;
                vu.b = *(const bf16x4*)((const char*)Vts + (d * 16 + l16) * 256 + vg * 16 + (q & 1) * 8);
                o[d] = __builtin_amdgcn_mfma_f32_16x16x16bf16_1k(vu.s, pu.s, o[d], 0, 0, 0);
            }
        }
    }
    lacc += __shfl_xor(lacc, 16);
    lacc += __shfl_xor(lacc, 32);
    float inv = 1.0f / lacc;
    int rowg = qt * 64 + wave * 16 + l16;
    long base = ((long)b * SDIM + rowg) * DDIM + h * 64;
    #pragma unroll
    for (int d = 0; d < 4; d++) {
        bf16x4 w;
        #pragma unroll
        for (int r = 0; r < 4; r++) w[r] = (__bf16)(o[d][r] * inv);
        *(bf16x4*)&ctx[base + d * 16 + q * 4] = w;
    }
}

// ---------------- launch ----------------

extern "C" void kernel_launch(void* const* d_in, const int* in_sizes, int n_in,
                              void* d_out, int out_size, void* d_ws, size_t ws_size,
                              hipStream_t stream) {
    const float* x = (const float*)d_in[0];
    const void* mask = d_in[1];
    const float* Wq = (const float*)d_in[2];
    const float* bq = (const float*)d_in[3];
    const float* Wk = (const float*)d_in[4];
    const float* bk = (const float*)d_in[5];
    const float* Wv = (const float*)d_in[6];
    const float* bv = (const float*)d_in[7];
    const float* Wo = (const float*)d_in[8];
    const float* bo = (const float*)d_in[9];
    const float* W1 = (const float*)d_in[10];
    const float* b1 = (const float*)d_in[11];
    const float* W2 = (const float*)d_in[12];
    const float* b2 = (const float*)d_in[13];

    char* ws = (char*)d_ws;
    __bf16* xb   = (__bf16*)(ws + 0);          // 16 MB; aliased as ctx after GEMM0
    __bf16* Qb   = (__bf16*)(ws + 16777216);   // 16 MB; aliased as attn_out after attention
    __bf16* Kb   = (__bf16*)(ws + 33554432);   // 16 MB (= Qb + QSZ)
    __bf16* Vtb  = (__bf16*)(ws + 50331648);   // 16 MB (= Qb + 2*QSZ)
    __bf16* Vrow = (__bf16*)(ws + 67108864);   // 16 MB (= Qb + 3*QSZ); dead after k_trv
    __bf16* hbuf = (__bf16*)(ws + 33554432);   // 64 MB (aliases Kb/Vtb/Vrow after attention)
    __bf16* wqkvt = (__bf16*)(ws + 100663296); // 6 MB
    __bf16* wot  = (__bf16*)(ws + 106954752);  // 2 MB
    __bf16* w1t  = (__bf16*)(ws + 109051904);  // 8 MB
    __bf16* w2t  = (__bf16*)(ws + 117440512);  // 8 MB
    float* bqkv  = (float*)(ws + 125829120);   // 12 KB
    int* flag    = (int*)(ws + 125841408);     // 4 B
    __bf16* ctx = xb;
    __bf16* attn_out = Qb;
    unsigned long long* bits = (unsigned long long*)wqkvt; // 2 MB, live after GEMM0
    (void)Vrow;

    k_f2b<<<8192, 256, 0, stream>>>(x, xb);
    k_pack_qkvw<<<3072, 256, 0, stream>>>(Wq, Wk, Wv, wqkvt);
    k_pack_qkvb<<<12, 256, 0, stream>>>(bq, bk, bv, bqkv);
    k_tr<<<1024, 256, 0, stream>>>(Wo, wot, 1024, 1024);
    k_tr<<<4096, 256, 0, stream>>>(W1, w1t, 1024, 4096);
    k_tr<<<4096, 256, 0, stream>>>(W2, w2t, 4096, 1024);
    k_probe<<<1, 256, 0, stream>>>((const unsigned*)mask, flag);

    {   // QKV projection: [8192,1024] x [3072,1024]^T; V written coalesced to Vrow
        dim3 g(64, 24);
        k_gemm<0><<<g, 256, 0, stream>>>(xb, wqkvt, bqkv, (void*)Qb, 3072, 1024);
    }
    k_trv<<<4096, 256, 0, stream>>>(Vrow, Vtb);
    k_pack_mask<<<65536, 256, 0, stream>>>(mask, flag, bits);
    k_attn<<<2048, 256, 0, stream>>>(Qb, Kb, Vtb, (const unsigned*)bits, ctx);
    {   // output projection
        dim3 g(64, 8);
        k_gemm<1><<<g, 256, 0, stream>>>(ctx, wot, bo, (void*)attn_out, 1024, 1024);
    }
    {   // FFN1 + relu
        dim3 g(64, 32);
        k_gemm<2><<<g, 256, 0, stream>>>(attn_out, w1t, b1, (void*)hbuf, 4096, 1024);
    }
    {   // FFN2 -> fp32 out
        dim3 g(64, 8);
        k_gemm<3><<<g, 256, 0, stream>>>(hbuf, w2t, b2, d_out, 1024, 4096);
    }
}

// Round 6
// 584.873 us; speedup vs baseline: 1.9926x; 1.0853x over previous
//
#include <hip/hip_runtime.h>
#include <hip/hip_bf16.h>

// EncoderLayer: B=4,S=2048,D=1024,H=16,DH=64,DFF=4096
// prep -> GEMM0 qkv (Q pre-scaled by log2e/sqrt(S)) -> k_trv -> mask bits -> remap
//   -> flash-attn (S^T, no-max softmax, hoisted LDS addrs, ones-MFMA l) -> GEMM1 -> GEMM2 -> GEMM3

#define SDIM 2048
#define DDIM 1024

using floatx4 = __attribute__((ext_vector_type(4))) float;
using bf16x8  = __attribute__((ext_vector_type(8))) __bf16;
using bf16x4  = __attribute__((ext_vector_type(4))) __bf16;
using short4v = __attribute__((ext_vector_type(4))) short;

#define GLDS16(gptr, lptr)                                                        \
    __builtin_amdgcn_global_load_lds(                                             \
        (const __attribute__((address_space(1))) void*)(uintptr_t)(gptr),         \
        (__attribute__((address_space(3))) void*)(uintptr_t)(lptr), 16, 0, 0)

// ---------------- prep kernels ----------------

__global__ void k_f2b(const float* __restrict__ in, __bf16* __restrict__ out) {
    long i = ((long)blockIdx.x * 256 + threadIdx.x) * 4;
    float4 f = *(const float4*)(in + i);
    bf16x4 v;
    v[0] = (__bf16)f.x; v[1] = (__bf16)f.y; v[2] = (__bf16)f.z; v[3] = (__bf16)f.w;
    *(bf16x4*)(out + i) = v;
}

__global__ void k_tr(const float* __restrict__ in, __bf16* __restrict__ out, int R, int C) {
    __shared__ float t[32][33];
    int nrt = R >> 5;
    int tr = blockIdx.x % nrt, tc = blockIdx.x / nrt;
    int r0 = tr * 32, c0 = tc * 32;
    int lx = threadIdx.x & 31, ly = threadIdx.x >> 5;
    #pragma unroll
    for (int i = 0; i < 32; i += 8) t[ly + i][lx] = in[(long)(r0 + ly + i) * C + c0 + lx];
    __syncthreads();
    #pragma unroll
    for (int i = 0; i < 32; i += 8) out[(long)(c0 + ly + i) * R + r0 + lx] = (__bf16)t[lx][ly + i];
}

__global__ void k_pack_qkvw(const float* __restrict__ Wq, const float* __restrict__ Wk,
                            const float* __restrict__ Wv, __bf16* __restrict__ out) {
    int bid = blockIdx.x;
    int dht = bid & 1;
    int dt = (bid >> 1) & 31;
    int h = (bid >> 6) & 15;
    int which = bid >> 10;
    const float* W = (which == 0) ? Wq : (which == 1) ? Wk : Wv;
    __shared__ float t[32][33];
    int lx = threadIdx.x & 31, ly = threadIdx.x >> 5;
    const float* src = W + ((long)h * 1024 + dt * 32) * 64 + dht * 32;
    #pragma unroll
    for (int i = 0; i < 32; i += 8) t[ly + i][lx] = src[(ly + i) * 64 + lx];
    __syncthreads();
    __bf16* dst = out + ((long)(which * 1024 + h * 64 + dht * 32)) * 1024 + dt * 32;
    #pragma unroll
    for (int i = 0; i < 32; i += 8) dst[(long)(ly + i) * 1024 + lx] = (__bf16)t[lx][ly + i];
}

__global__ void k_pack_qkvb(const float* bq, const float* bk, const float* bv, float* out) {
    int i = blockIdx.x * 256 + threadIdx.x;
    if (i < 3072) {
        int which = i >> 10, r = i & 1023;
        const float* s = (which == 0) ? bq : (which == 1) ? bk : bv;
        out[i] = s[r];
    }
}

__global__ void k_probe(const unsigned* __restrict__ m, int* flag) {
    __shared__ int bad;
    if (threadIdx.x == 0) bad = 0;
    __syncthreads();
    int local = 0;
    for (int i = 0; i < 64; i++) {
        unsigned w = m[threadIdx.x + 256 * i];
        if (w != 0u && w != 1u && w != 0x3f800000u) local = 1;
    }
    if (local) atomicOr(&bad, 1);
    __syncthreads();
    if (threadIdx.x == 0) *flag = bad ? 0 : 1;
}

__global__ void k_pack_mask(const void* __restrict__ mask, const int* __restrict__ flag,
                            unsigned long long* __restrict__ bits) {
    long wid = ((long)blockIdx.x * 256 + threadIdx.x) >> 6;
    int lane = threadIdx.x & 63;
    long e = wid * 64 + lane;
    bool pred;
    if (*flag) pred = ((const unsigned*)mask)[e] != 0u;
    else       pred = ((const unsigned char*)mask)[e] != 0;
    unsigned long long bal = __ballot(pred);
    if (lane == 0) bits[wid] = bal;
}

// remap mask bits to per-lane words: out[((b*S+s)*16 + kt)*4 + q], bit ct*4+r = mask[s][kt*128+ct*16+q*4+r]
__global__ void k_remap(const unsigned* __restrict__ bitsDW, unsigned* __restrict__ out) {
    int t = blockIdx.x * 256 + threadIdx.x;  // [s:13][kt:4][q:2]
    int q = t & 3, kt = (t >> 2) & 15, srow = t >> 6;
    uint4 md = *(const uint4*)(bitsDW + (long)srow * 64 + kt * 4);
    unsigned d[4] = {md.x, md.y, md.z, md.w};
    unsigned acc = 0;
    #pragma unroll
    for (int ct = 0; ct < 8; ct++) {
        unsigned nib = (d[ct >> 1] >> (((ct & 1) << 4) + q * 4)) & 0xFu;
        acc |= nib << (ct * 4);
    }
    out[t] = acc;
}

// V row-layout [pair][2048][64] -> Vt [pair][64][2048]
__global__ void k_trv(const __bf16* __restrict__ Vrow, __bf16* __restrict__ Vt) {
    __shared__ __bf16 t[32][72];
    int p = blockIdx.x >> 6, ts = blockIdx.x & 63;
    int tid = threadIdx.x;
    const __bf16* src = Vrow + ((long)p * 2048 + ts * 32) * 64;
    int s = tid >> 3, c = (tid & 7) * 8;
    *(bf16x8*)&t[s][c] = *(const bf16x8*)&src[s * 64 + c];
    __syncthreads();
    int dh = tid >> 2, sb = (tid & 3) * 8;
    bf16x8 w;
    #pragma unroll
    for (int j = 0; j < 8; j++) w[j] = t[sb + j][dh];
    *(bf16x8*)&Vt[((long)p * 64 + dh) * 2048 + ts * 32 + sb] = w;
}

// ---------------- GEMM: BK=64, GLDS staging, rotated granules, hoisted read addrs ----------------
#define QSZ 8388608L

template <int MODE>
__global__ __launch_bounds__(256, 4) void k_gemm(const __bf16* __restrict__ A,
                                                 const __bf16* __restrict__ Bt,
                                                 const float* __restrict__ bias,
                                                 void* __restrict__ Cout, int Ndim, int K) {
    __shared__ __align__(16) __bf16 As[128 * 64];
    __shared__ __align__(16) __bf16 Bs[128 * 64];
    const int tid = threadIdx.x;
    const int wave = tid >> 6, lane = tid & 63;
    const int q = lane >> 4, l16 = lane & 15;
    const int wr = wave >> 1, wc = wave & 1;
    const long bm = (long)blockIdx.x * 128;
    const long bn = (long)blockIdx.y * 128;
    floatx4 acc[4][4] = {};

    const int srow = lane >> 3;
    const int scol = (((lane & 7) - srow) & 7) * 8;
    const int r8 = l16 & 7;

    // hoisted LDS read bases (per-iter reads use imm offsets only)
    const char* apA0 = (const char*)As + (wr * 64 + l16) * 128 + ((q + r8) & 7) * 16;
    const char* apA1 = (const char*)As + (wr * 64 + l16) * 128 + ((q + 4 + r8) & 7) * 16;
    const char* apB0 = (const char*)Bs + (wc * 64 + l16) * 128 + ((q + r8) & 7) * 16;
    const char* apB1 = (const char*)Bs + (wc * 64 + l16) * 128 + ((q + 4 + r8) & 7) * 16;

    for (int k0 = 0; k0 < K; k0 += 64) {
        __syncthreads();
        #pragma unroll
        for (int c = 0; c < 4; c++) {
            int row0 = wave * 32 + c * 8;
            GLDS16(&A[(bm + row0 + srow) * K + k0 + scol], (char*)As + row0 * 128);
            GLDS16(&Bt[(bn + row0 + srow) * K + k0 + scol], (char*)Bs + row0 * 128);
        }
        __syncthreads();
        bf16x8 af[4], bfr[4];
        #pragma unroll
        for (int i = 0; i < 4; i++) af[i] = *(const bf16x8*)(apA0 + i * 2048);
        #pragma unroll
        for (int j = 0; j < 4; j++) bfr[j] = *(const bf16x8*)(apB0 + j * 2048);
        #pragma unroll
        for (int i = 0; i < 4; i++)
            #pragma unroll
            for (int j = 0; j < 4; j++)
                acc[i][j] = __builtin_amdgcn_mfma_f32_16x16x32_bf16(af[i], bfr[j], acc[i][j], 0, 0, 0);
        #pragma unroll
        for (int i = 0; i < 4; i++) af[i] = *(const bf16x8*)(apA1 + i * 2048);
        #pragma unroll
        for (int j = 0; j < 4; j++) bfr[j] = *(const bf16x8*)(apB1 + j * 2048);
        #pragma unroll
        for (int i = 0; i < 4; i++)
            #pragma unroll
            for (int j = 0; j < 4; j++)
                acc[i][j] = __builtin_amdgcn_mfma_f32_16x16x32_bf16(af[i], bfr[j], acc[i][j], 0, 0, 0);
    }

    const int mrow0 = (int)bm + wr * 64 + q * 4;
    const int ncol0 = (int)bn + wc * 64;
    #pragma unroll
    for (int j = 0; j < 4; j++) {
        int nbase = ncol0 + j * 16 + l16;
        float bv = bias[nbase];
        #pragma unroll
        for (int i = 0; i < 4; i++) {
            #pragma unroll
            for (int r = 0; r < 4; r++) {
                int mm = mrow0 + i * 16 + r;
                float v = acc[i][j][r] + bv;
                if (MODE == 2) v = fmaxf(v, 0.f);
                if (MODE == 3) {
                    ((float*)Cout)[(long)mm * Ndim + nbase] = v;
                } else if (MODE == 0) {
                    int which = nbase >> 10, rem = nbase & 1023;
                    int hh = rem >> 6, dh = rem & 63;
                    int bb = mm >> 11, ss = mm & 2047;
                    long pr = (long)(bb * 16 + hh);
                    __bf16* o = (__bf16*)Cout;
                    if (which == 0) {
                        v *= 0.03188152837f; // log2(e)/sqrt(2048): softmax in exp2 domain
                        o[(pr * 2048 + ss) * 64 + dh] = (__bf16)v;
                    } else if (which == 1) o[QSZ + (pr * 2048 + ss) * 64 + dh] = (__bf16)v;
                    else o[3 * QSZ + (pr * 2048 + ss) * 64 + dh] = (__bf16)v;
                } else {
                    ((__bf16*)Cout)[(long)mm * Ndim + nbase] = (__bf16)v;
                }
            }
        }
    }
}

// ---------------- flash attention ----------------
// S^T form; no-max softmax in exp2 domain; per-lane mask word (bit ct*4+r);
// l accumulated by ones-A MFMA alongside PV; all LDS read addrs hoisted.
__global__ __launch_bounds__(256, 4) void k_attn(const __bf16* __restrict__ Q,
                                                 const __bf16* __restrict__ Kb,
                                                 const __bf16* __restrict__ Vt,
                                                 const unsigned* __restrict__ bitw2,
                                                 __bf16* __restrict__ ctx) {
    __shared__ __align__(16) __bf16 Qs[64 * 64];
    __shared__ __align__(16) __bf16 Ks[128 * 64];
    __shared__ __align__(16) __bf16 Vts[64 * 128];
    const int tid = threadIdx.x, wave = tid >> 6, lane = tid & 63;
    const int q = lane >> 4, l16 = lane & 15;
    const int pair = blockIdx.x & 63, qt = blockIdx.x >> 6;
    const int b = pair >> 4, h = pair & 15;

    const int srow8 = lane >> 3;
    const int scol8 = (((lane & 7) - srow8) & 7) * 8;
    const int r8 = l16 & 7;
    const int vrow = lane >> 4;
    const int vl = lane & 15;

    const __bf16* Qp = Q + ((long)pair * SDIM + qt * 64) * 64;
    #pragma unroll
    for (int c = 0; c < 2; c++) {
        int row0 = wave * 16 + c * 8;
        GLDS16(&Qp[(row0 + srow8) * 64 + scol8], (char*)Qs + row0 * 128);
    }
    __syncthreads();
    const bf16x8 qf0 = *(const bf16x8*)((const char*)Qs + (wave * 16 + l16) * 128 + ((q + r8) & 7) * 16);
    const bf16x8 qf1 = *(const bf16x8*)((const char*)Qs + (wave * 16 + l16) * 128 + ((q + 4 + r8) & 7) * 16);

    // hoisted LDS read bases
    const char* kp0 = (const char*)Ks + l16 * 128 + ((q + r8) & 7) * 16;
    const char* kp1 = (const char*)Ks + l16 * 128 + ((q + 4 + r8) & 7) * 16;
    const char* vp[8];
    #pragma unroll
    for (int ct = 0; ct < 8; ct++)
        vp[ct] = (const char*)Vts + l16 * 256 + (q & 1) * 8 + ((ct * 2 + (q >> 1) + l16) & 15) * 16;
    const int qrow = qt * 64 + wave * 16 + l16;
    const unsigned* mp = bitw2 + ((long)(b * SDIM + qrow)) * 64 + q;

    floatx4 o[4] = {};
    floatx4 o5 = {};
    union { unsigned u; short4v s4; float f; } tmp;
    short4v ones;
    { union { unsigned u[2]; short4v s; } c; c.u[0] = 0x3F803F80u; c.u[1] = 0x3F803F80u; ones = c.s; }

    for (int kt = 0; kt < 16; kt++) {
        __syncthreads();
        const __bf16* Kp = Kb + ((long)pair * SDIM + kt * 128) * 64;
        #pragma unroll
        for (int c = 0; c < 4; c++) {
            int row0 = wave * 32 + c * 8;
            GLDS16(&Kp[(row0 + srow8) * 64 + scol8], (char*)Ks + row0 * 128);
        }
        const __bf16* Vp = Vt + ((long)pair * 64) * SDIM + kt * 128;
        #pragma unroll
        for (int c = 0; c < 4; c++) {
            int row0 = wave * 16 + c * 4;
            int gsrc = ((vl - (c * 4 + vrow)) & 15) * 8;
            GLDS16(&Vp[(long)(row0 + vrow) * SDIM + gsrc], (char*)Vts + row0 * 256);
        }
        const unsigned w32 = mp[kt * 4];
        __syncthreads();

        // S^T = K·Q^T (exp2 domain)
        floatx4 st[8];
        #pragma unroll
        for (int ct = 0; ct < 8; ct++) {
            bf16x8 kf0 = *(const bf16x8*)(kp0 + ct * 2048);
            bf16x8 kf1 = *(const bf16x8*)(kp1 + ct * 2048);
            floatx4 z = {};
            z = __builtin_amdgcn_mfma_f32_16x16x32_bf16(kf0, qf0, z, 0, 0, 0);
            z = __builtin_amdgcn_mfma_f32_16x16x32_bf16(kf1, qf1, z, 0, 0, 0);
            st[ct] = z;
        }
        // p = exp2(s), mask (constant-literal bit tests), pack via v_perm, PV + ones-MFMA
        #pragma unroll
        for (int ct = 0; ct < 8; ct++) {
            float p0 = __builtin_amdgcn_exp2f(st[ct][0]);
            float p1 = __builtin_amdgcn_exp2f(st[ct][1]);
            float p2 = __builtin_amdgcn_exp2f(st[ct][2]);
            float p3 = __builtin_amdgcn_exp2f(st[ct][3]);
            p0 = (w32 & (1u << (ct * 4 + 0))) ? 0.f : p0;
            p1 = (w32 & (1u << (ct * 4 + 1))) ? 0.f : p1;
            p2 = (w32 & (1u << (ct * 4 + 2))) ? 0.f : p2;
            p3 = (w32 & (1u << (ct * 4 + 3))) ? 0.f : p3;
            union { float f; unsigned u; } c0, c1, c2, c3;
            c0.f = p0; c1.f = p1; c2.f = p2; c3.f = p3;
            union { unsigned u[2]; short4v s; } pu;
            pu.u[0] = __builtin_amdgcn_perm(c1.u, c0.u, 0x07060302u);
            pu.u[1] = __builtin_amdgcn_perm(c3.u, c2.u, 0x07060302u);
            #pragma unroll
            for (int d = 0; d < 4; d++) {
                union { bf16x4 b; short4v s; } vu;
                vu.b = *(const bf16x4*)(vp[ct] + d * 4096);
                o[d] = __builtin_amdgcn_mfma_f32_16x16x16bf16_1k(vu.s, pu.s, o[d], 0, 0, 0);
            }
            o5 = __builtin_amdgcn_mfma_f32_16x16x16bf16_1k(ones, pu.s, o5, 0, 0, 0);
        }
    }
    float inv = 1.0f / o5[0];
    long base = ((long)b * SDIM + qrow) * DDIM + h * 64;
    #pragma unroll
    for (int d = 0; d < 4; d++) {
        bf16x4 w;
        #pragma unroll
        for (int r = 0; r < 4; r++) w[r] = (__bf16)(o[d][r] * inv);
        *(bf16x4*)&ctx[base + d * 16 + q * 4] = w;
    }
}

// ---------------- launch ----------------

extern "C" void kernel_launch(void* const* d_in, const int* in_sizes, int n_in,
                              void* d_out, int out_size, void* d_ws, size_t ws_size,
                              hipStream_t stream) {
    const float* x = (const float*)d_in[0];
    const void* mask = d_in[1];
    const float* Wq = (const float*)d_in[2];
    const float* bq = (const float*)d_in[3];
    const float* Wk = (const float*)d_in[4];
    const float* bk = (const float*)d_in[5];
    const float* Wv = (const float*)d_in[6];
    const float* bv = (const float*)d_in[7];
    const float* Wo = (const float*)d_in[8];
    const float* bo = (const float*)d_in[9];
    const float* W1 = (const float*)d_in[10];
    const float* b1 = (const float*)d_in[11];
    const float* W2 = (const float*)d_in[12];
    const float* b2 = (const float*)d_in[13];

    char* ws = (char*)d_ws;
    __bf16* xb   = (__bf16*)(ws + 0);          // 16 MB; aliased as ctx after GEMM0
    __bf16* Qb   = (__bf16*)(ws + 16777216);   // 16 MB; aliased as attn_out after attention
    __bf16* Kb   = (__bf16*)(ws + 33554432);   // 16 MB (= Qb + QSZ)
    __bf16* Vtb  = (__bf16*)(ws + 50331648);   // 16 MB (= Qb + 2*QSZ)
    __bf16* Vrow = (__bf16*)(ws + 67108864);   // 16 MB (= Qb + 3*QSZ); dead after k_trv
    __bf16* hbuf = (__bf16*)(ws + 33554432);   // 64 MB (aliases Kb/Vtb/Vrow after attention)
    __bf16* wqkvt = (__bf16*)(ws + 100663296); // 6 MB (bits/bits2 alias after GEMM0)
    __bf16* wot  = (__bf16*)(ws + 106954752);  // 2 MB
    __bf16* w1t  = (__bf16*)(ws + 109051904);  // 8 MB
    __bf16* w2t  = (__bf16*)(ws + 117440512);  // 8 MB
    float* bqkv  = (float*)(ws + 125829120);   // 12 KB
    int* flag    = (int*)(ws + 125841408);     // 4 B
    __bf16* ctx = xb;
    __bf16* attn_out = Qb;
    unsigned long long* bits = (unsigned long long*)wqkvt;           // 2 MB
    unsigned* bits2 = (unsigned*)((char*)wqkvt + 2097152);           // 2 MB
    (void)Vrow;

    k_f2b<<<8192, 256, 0, stream>>>(x, xb);
    k_pack_qkvw<<<3072, 256, 0, stream>>>(Wq, Wk, Wv, wqkvt);
    k_pack_qkvb<<<12, 256, 0, stream>>>(bq, bk, bv, bqkv);
    k_tr<<<1024, 256, 0, stream>>>(Wo, wot, 1024, 1024);
    k_tr<<<4096, 256, 0, stream>>>(W1, w1t, 1024, 4096);
    k_tr<<<4096, 256, 0, stream>>>(W2, w2t, 4096, 1024);
    k_probe<<<1, 256, 0, stream>>>((const unsigned*)mask, flag);

    {   // QKV projection: [8192,1024] x [3072,1024]^T; V written coalesced to Vrow
        dim3 g(64, 24);
        k_gemm<0><<<g, 256, 0, stream>>>(xb, wqkvt, bqkv, (void*)Qb, 3072, 1024);
    }
    k_trv<<<4096, 256, 0, stream>>>(Vrow, Vtb);
    k_pack_mask<<<65536, 256, 0, stream>>>(mask, flag, bits);
    k_remap<<<2048, 256, 0, stream>>>((const unsigned*)bits, bits2);
    k_attn<<<2048, 256, 0, stream>>>(Qb, Kb, Vtb, bits2, ctx);
    {   // output projection
        dim3 g(64, 8);
        k_gemm<1><<<g, 256, 0, stream>>>(ctx, wot, bo, (void*)attn_out, 1024, 1024);
    }
    {   // FFN1 + relu
        dim3 g(64, 32);
        k_gemm<2><<<g, 256, 0, stream>>>(attn_out, w1t, b1, (void*)hbuf, 4096, 1024);
    }
    {   // FFN2 -> fp32 out
        dim3 g(64, 8);
        k_gemm<3><<<g, 256, 0, stream>>>(hbuf, w2t, b2, d_out, 1024, 4096);
    }
}